// Round 11
// baseline (418.659 us; speedup 1.0000x reference)
//
#include <hip/hip_runtime.h>
#include <hip/hip_bf16.h>
#include <math.h>

#define NN_F_IN   512
#define NN_HID    256
#define NN_HEADS  8
#define NN_FH     32
#define NN_NCLASS 40
#define TAU_F     0.5f
#define LAMDA_F   0.5f
// sqrt(2 * log2(e)) : makes gram epilogue a bare exp2
#define ZN_SCALE  1.6986436f

typedef __attribute__((ext_vector_type(8))) short bf16x8;
typedef __attribute__((ext_vector_type(4))) float f32x4;

static __device__ __forceinline__ float lrelu02(float x) { return x >= 0.f ? x : 0.2f * x; }
static __device__ __forceinline__ float elu1(float x)    { return x > 0.f ? x : expm1f(x); }
static __device__ __forceinline__ float b2f(unsigned short u) {
    unsigned int x = ((unsigned int)u) << 16;
    return __uint_as_float(x);
}
static __device__ __forceinline__ unsigned short f2b(float f) {
    __hip_bfloat16 hb = __float2bfloat16(f);
    return *reinterpret_cast<unsigned short*>(&hb);
}

// ---------------------------------------------------------------------------
// Fused prep: X cast (float4-wide) + 4 transposed W casts, one launch.
// ---------------------------------------------------------------------------
__global__ void prep_kernel(const float* __restrict__ x,
                            const float* __restrict__ W0, const float* __restrict__ W1,
                            const float* __restrict__ W2, const float* __restrict__ Wo,
                            unsigned short* __restrict__ Xb,
                            unsigned short* __restrict__ Wt0, unsigned short* __restrict__ Wt1,
                            unsigned short* __restrict__ Wt2, unsigned short* __restrict__ Wto,
                            int n4X) {
    int i = blockIdx.x * 256 + threadIdx.x;
    if (i < n4X) {
        float4 v = *(const float4*)(x + (size_t)i * 4);
        ushort4 o;
        o.x = f2b(v.x); o.y = f2b(v.y); o.z = f2b(v.z); o.w = f2b(v.w);
        *(ushort4*)(Xb + (size_t)i * 4) = o;
        return;
    }
    i -= n4X;
    if (i < 256 * 512) {            // Wt0: Np=256, K=512, Nc=256
        int np = i >> 9, k = i & 511;
        Wt0[i] = f2b(W0[(size_t)k * 256 + np]);
        return;
    }
    i -= 256 * 512;
    if (i < 256 * 256) {            // Wt1
        int np = i >> 8, k = i & 255;
        Wt1[i] = f2b(W1[(size_t)k * 256 + np]);
        return;
    }
    i -= 256 * 256;
    if (i < 256 * 256) {            // Wt2
        int np = i >> 8, k = i & 255;
        Wt2[i] = f2b(W2[(size_t)k * 256 + np]);
        return;
    }
    i -= 256 * 256;
    if (i < 384 * 256) {            // Wto: Np=384, K=256, Nc=320
        int np = i >> 8, k = i & 255;
        Wto[i] = f2b(np < 320 ? Wo[(size_t)k * 320 + np] : 0.f);
    }
}

// ---------------------------------------------------------------------------
// MFMA GEMM: H[m][col] = sum_k A[m][k] * B[col][k], A/B bf16, H bf16.
// Block = 4 waves 2x2 -> 64x64 tile; wave = 32x32 = 2x2 frags of 16x16x32.
// ---------------------------------------------------------------------------
__global__ __launch_bounds__(256) void fc_mfma(const unsigned short* __restrict__ A,
                                               const unsigned short* __restrict__ B,
                                               unsigned short* __restrict__ H,
                                               int M, int K, int ncols, int ldH) {
    int t = threadIdx.x, lane = t & 63, wid = t >> 6;
    int wrow = wid >> 1, wcol = wid & 1;
    int l15 = lane & 15, lg = lane >> 4;
    int mbase = blockIdx.y * 64 + wrow * 32;
    int nbase = blockIdx.x * 64 + wcol * 32;

    const unsigned short* Ap[2];
    const unsigned short* Bp[2];
#pragma unroll
    for (int m = 0; m < 2; ++m) {
        int rr = mbase + m * 16 + l15;
        if (rr > M - 1) rr = M - 1;
        Ap[m] = A + (size_t)rr * K + lg * 8;
        Bp[m] = B + (size_t)(nbase + m * 16 + l15) * K + lg * 8;
    }
    f32x4 acc[2][2];
#pragma unroll
    for (int m = 0; m < 2; ++m)
#pragma unroll
        for (int nn = 0; nn < 2; ++nn)
#pragma unroll
            for (int r = 0; r < 4; ++r) acc[m][nn][r] = 0.f;

    bf16x8 aP[2], bP[2], aQ[2], bQ[2];
#pragma unroll
    for (int m = 0; m < 2; ++m) {
        aP[m] = *(const bf16x8*)(Ap[m]);
        bP[m] = *(const bf16x8*)(Bp[m]);
    }
    int nhalf = K >> 6;
    int kk = 32;
    for (int it = 0; it < nhalf; ++it) {
#pragma unroll
        for (int m = 0; m < 2; ++m) {
            aQ[m] = *(const bf16x8*)(Ap[m] + kk);
            bQ[m] = *(const bf16x8*)(Bp[m] + kk);
        }
#pragma unroll
        for (int m = 0; m < 2; ++m)
#pragma unroll
            for (int nn = 0; nn < 2; ++nn)
                acc[m][nn] = __builtin_amdgcn_mfma_f32_16x16x32_bf16(aP[m], bP[nn], acc[m][nn], 0, 0, 0);
        if (it + 1 < nhalf) {
#pragma unroll
            for (int m = 0; m < 2; ++m) {
                aP[m] = *(const bf16x8*)(Ap[m] + kk + 32);
                bP[m] = *(const bf16x8*)(Bp[m] + kk + 32);
            }
        }
#pragma unroll
        for (int m = 0; m < 2; ++m)
#pragma unroll
            for (int nn = 0; nn < 2; ++nn)
                acc[m][nn] = __builtin_amdgcn_mfma_f32_16x16x32_bf16(aQ[m], bQ[nn], acc[m][nn], 0, 0, 0);
        kk += 64;
    }
#pragma unroll
    for (int m = 0; m < 2; ++m) {
#pragma unroll
        for (int nn = 0; nn < 2; ++nn) {
            int col = nbase + nn * 16 + l15;
            if (col >= ncols) continue;
#pragma unroll
            for (int r = 0; r < 4; ++r) {
                int row = mbase + m * 16 + lg * 4 + r;
                if (row < M) H[(size_t)row * ldH + col] = f2b(acc[m][nn][r]);
            }
        }
    }
}

// ---------------------------------------------------------------------------
// es/ed dot products (Hm bf16)
// ---------------------------------------------------------------------------
__global__ void attn_kernel(const unsigned short* __restrict__ Hm, const float* __restrict__ As,
                            const float* __restrict__ Ad, float* __restrict__ es,
                            float* __restrict__ ed, int n, int df) {
    int idx = blockIdx.x * blockDim.x + threadIdx.x;
    if (idx >= n * NN_HEADS) return;
    int nn = idx / NN_HEADS, hh = idx - nn * NN_HEADS;
    const unsigned short* hp = Hm + (size_t)nn * NN_HEADS * df + hh * df;
    const float* ap = As + hh * df;
    const float* bp = Ad + hh * df;
    float s1 = 0.f, s2 = 0.f;
    for (int d = 0; d < df; d += 4) {
        ushort4 hv = *(const ushort4*)(hp + d);
        float4 av = *(const float4*)(ap + d);
        float4 bv = *(const float4*)(bp + d);
        float h0 = b2f(hv.x), h1 = b2f(hv.y), h2 = b2f(hv.z), h3 = b2f(hv.w);
        s1 += h0 * av.x + h1 * av.y + h2 * av.z + h3 * av.w;
        s2 += h0 * bv.x + h1 * bv.y + h2 * bv.z + h3 * bv.w;
    }
    es[idx] = s1;
    ed[idx] = s2;
}

// ---------------------------------------------------------------------------
// Edge weights: one fast-exp per (edge,head). wC[p][h] CSR order, zinv[n][h].
// ---------------------------------------------------------------------------
__global__ __launch_bounds__(256) void edge_wz(
    const float* __restrict__ es, const float* __restrict__ ed,
    const int* __restrict__ csr_src, const int* __restrict__ row_start,
    float* __restrict__ wC, float* __restrict__ zinv, int n) {
    int lane = threadIdx.x & 63;
    int nn   = blockIdx.x * 4 + (threadIdx.x >> 6);
    if (nn >= n) return;
    int s0 = row_start[nn], s1 = row_start[nn + 1];
    int h    = lane & 7;
    int slot = lane >> 3;
    float edh = ed[nn * NN_HEADS + h];
    float z = 0.f;
    for (int e = s0 + slot; e < s1; e += 8) {
        int sv = csr_src[e];
        float w = __expf(lrelu02(es[sv * NN_HEADS + h] + edh));
        wC[(size_t)e * NN_HEADS + h] = w;
        z += w;
    }
    z += __shfl_xor(z, 8, 64);
    z += __shfl_xor(z, 16, 64);
    z += __shfl_xor(z, 32, 64);
    if (slot == 0) zinv[nn * NN_HEADS + h] = 1.f / z;
}

// ---------------------------------------------------------------------------
// CSR build
// ---------------------------------------------------------------------------
__global__ void count_kernel(const int* __restrict__ dst, int* __restrict__ counts, int E) {
    int e = blockIdx.x * blockDim.x + threadIdx.x;
    if (e < E) atomicAdd(&counts[dst[e]], 1);
}

__global__ void scan_kernel(const int* __restrict__ counts, int* __restrict__ row_start,
                            int* __restrict__ cursor, int n) {
    __shared__ int s[1024];
    int t  = threadIdx.x;
    int ch = (n + 1023) / 1024;
    int lo = t * ch;
    int sum = 0;
    for (int j = 0; j < ch; ++j) {
        int i = lo + j;
        if (i < n) sum += counts[i];
    }
    s[t] = sum;
    __syncthreads();
    for (int off = 1; off < 1024; off <<= 1) {
        int v = 0;
        if (t >= off) v = s[t - off];
        __syncthreads();
        s[t] += v;
        __syncthreads();
    }
    int run = (t == 0) ? 0 : s[t - 1];
    for (int j = 0; j < ch; ++j) {
        int i = lo + j;
        if (i < n) {
            row_start[i] = run;
            cursor[i] = run;
            run += counts[i];
        }
    }
    if (t == 1023) row_start[n] = s[1023];
}

__global__ void scatter_kernel(const int* __restrict__ src, const int* __restrict__ dst,
                               int* __restrict__ cursor, int* __restrict__ csr_src, int E) {
    int e = blockIdx.x * blockDim.x + threadIdx.x;
    if (e < E) {
        int d   = dst[e];
        int pos = atomicAdd(&cursor[d], 1);
        csr_src[pos] = src[e];
    }
}

// ---------------------------------------------------------------------------
// Hidden-layer gather: weighted sum; guard-free full batches + guarded tail.
// ---------------------------------------------------------------------------
__global__ __launch_bounds__(256) void gather_hidden(
    const unsigned short* __restrict__ Hm, const float* __restrict__ wC,
    const float* __restrict__ zinv, const int* __restrict__ csr_src,
    const int* __restrict__ row_start, const unsigned short* __restrict__ last,
    unsigned short* __restrict__ out, int n, float beta) {
    int lane = threadIdx.x & 63;
    int nn   = blockIdx.x * 4 + (threadIdx.x >> 6);
    if (nn >= n) return;
    int s0 = row_start[nn], s1 = row_start[nn + 1];
    int h2 = lane >> 3;

    float a0 = 0.f, a1 = 0.f, a2 = 0.f, a3 = 0.f;
    int fullEnd = s0 + ((s1 - s0) & ~7);
    int e = s0;
    for (; e < fullEnd; e += 8) {
        int idx[8];
        float wv[8];
#pragma unroll
        for (int j = 0; j < 8; ++j) {
            idx[j] = csr_src[e + j];
            wv[j]  = wC[(size_t)(e + j) * NN_HEADS + h2];
        }
        ushort4 r[8];
#pragma unroll
        for (int j = 0; j < 8; ++j) r[j] = *(const ushort4*)&Hm[(size_t)idx[j] * NN_HID + lane * 4];
#pragma unroll
        for (int j = 0; j < 8; ++j) {
            float w = wv[j];
            a0 += w * b2f(r[j].x); a1 += w * b2f(r[j].y);
            a2 += w * b2f(r[j].z); a3 += w * b2f(r[j].w);
        }
    }
    if (e < s1) {
        int c = s1 - e;
        int idx[8];
        float wv[8];
#pragma unroll
        for (int j = 0; j < 8; ++j) {
            int p = (j < c) ? e + j : e;
            idx[j] = csr_src[p];
            wv[j]  = wC[(size_t)p * NN_HEADS + h2];
        }
        ushort4 r[8];
#pragma unroll
        for (int j = 0; j < 8; ++j) r[j] = *(const ushort4*)&Hm[(size_t)idx[j] * NN_HID + lane * 4];
#pragma unroll
        for (int j = 0; j < 8; ++j) {
            if (j < c) {
                float w = wv[j];
                a0 += w * b2f(r[j].x); a1 += w * b2f(r[j].y);
                a2 += w * b2f(r[j].z); a3 += w * b2f(r[j].w);
            }
        }
    }
    float zi = zinv[nn * NN_HEADS + h2];
    float v0 = elu1(a0 * zi), v1 = elu1(a1 * zi), v2 = elu1(a2 * zi), v3 = elu1(a3 * zi);
    if (beta >= 0.f) {
        ushort4 lv = *(const ushort4*)&last[(size_t)nn * NN_HID + lane * 4];
        v0 = beta * b2f(lv.x) + (1.f - beta) * v0;
        v1 = beta * b2f(lv.y) + (1.f - beta) * v1;
        v2 = beta * b2f(lv.z) + (1.f - beta) * v2;
        v3 = beta * b2f(lv.w) + (1.f - beta) * v3;
    }
    ushort4 o;
    o.x = f2b(v0); o.y = f2b(v1); o.z = f2b(v2); o.w = f2b(v3);
    *(ushort4*)&out[(size_t)nn * NN_HID + lane * 4] = o;
}

// ---------------------------------------------------------------------------
// Final layer gather: weighted sum + head-mean + log_softmax -> d_out
// ---------------------------------------------------------------------------
__global__ void gather_final(const unsigned short* __restrict__ Hm, const float* __restrict__ wC,
                             const float* __restrict__ zinv, const int* __restrict__ csr_src,
                             const int* __restrict__ row_start, float* __restrict__ dout, int n) {
    int nn = blockIdx.x;
    __shared__ float accs[NN_HEADS * NN_NCLASS];
    int t = threadIdx.x;  // 0..319
    int s0 = row_start[nn], s1 = row_start[nn + 1];
    int hh = t / NN_NCLASS;
    float acc = 0.f;
    const int LD = NN_HEADS * NN_NCLASS;
    int fullEnd = s0 + ((s1 - s0) & ~7);
    int e = s0;
    for (; e < fullEnd; e += 8) {
        int idx[8];
        float wv[8];
#pragma unroll
        for (int j = 0; j < 8; ++j) {
            idx[j] = csr_src[e + j];
            wv[j]  = wC[(size_t)(e + j) * NN_HEADS + hh];
        }
        float v[8];
#pragma unroll
        for (int j = 0; j < 8; ++j) v[j] = b2f(Hm[(size_t)idx[j] * LD + t]);
#pragma unroll
        for (int j = 0; j < 8; ++j) acc += wv[j] * v[j];
    }
    if (e < s1) {
        int c = s1 - e;
        int idx[8];
        float wv[8];
#pragma unroll
        for (int j = 0; j < 8; ++j) {
            int p = (j < c) ? e + j : e;
            idx[j] = csr_src[p];
            wv[j]  = wC[(size_t)p * NN_HEADS + hh];
        }
        float v[8];
#pragma unroll
        for (int j = 0; j < 8; ++j) v[j] = b2f(Hm[(size_t)idx[j] * LD + t]);
#pragma unroll
        for (int j = 0; j < 8; ++j) {
            if (j < c) acc += wv[j] * v[j];
        }
    }
    accs[t] = acc * zinv[nn * NN_HEADS + hh];
    __syncthreads();
    if (t < 64) {
        float v = -INFINITY;
        if (t < NN_NCLASS) {
            float sacc = 0.f;
#pragma unroll
            for (int h2 = 0; h2 < NN_HEADS; ++h2) sacc += accs[h2 * NN_NCLASS + t];
            v = sacc * (1.f / NN_HEADS);
        }
        float mx = v;
#pragma unroll
        for (int o = 1; o < 64; o <<= 1) mx = fmaxf(mx, __shfl_xor(mx, o, 64));
        float ex = (t < NN_NCLASS) ? expf(v - mx) : 0.f;
        float se = ex;
#pragma unroll
        for (int o = 1; o < 64; o <<= 1) se += __shfl_xor(se, o, 64);
        if (t < NN_NCLASS) dout[(size_t)nn * NN_NCLASS + t] = (v - mx) - logf(se);
    }
}

// ---------------------------------------------------------------------------
// Row-normalize (bf16 in) + SCALED bf16 zn (pre-multiplied by sqrt(2*log2e)
// so gram epilogue is bare exp2) + analytic diagonal. Grid = Npad blocks:
// pad rows are zero-filled here (replaces the pad memset).
// ---------------------------------------------------------------------------
__global__ void rownorm_kernel(const unsigned short* __restrict__ z, short* __restrict__ znb,
                               float* __restrict__ dvec, int n) {
    int nn = blockIdx.x;
    int t  = threadIdx.x;  // 256
    if (nn >= n) {
        znb[(size_t)nn * NN_HID + t] = 0;
        return;
    }
    float v  = b2f(z[(size_t)nn * NN_HID + t]);
    float sq = v * v;
#pragma unroll
    for (int o = 1; o < 64; o <<= 1) sq += __shfl_xor(sq, o, 64);
    __shared__ float ws[4];
    if ((t & 63) == 0) ws[t >> 6] = sq;
    __syncthreads();
    float s = ws[0] + ws[1] + ws[2] + ws[3];
    float m = fmaxf(sqrtf(s), 1e-12f);
    znb[(size_t)nn * NN_HID + t] = (short)f2b((v / m) * ZN_SCALE);
    if (t == 0) dvec[nn] = __expf((s / (m * m)) * (1.f / TAU_F));
}

// ---------------------------------------------------------------------------
// Symmetric gram rowsums, 8-WAVE (512thr) 128x128 tile, BK=128, 3 barriers.
// Wave tile 64x32 (acc[4][2]); 2 wrow x 4 wcol. LDS: 4 slabs [128][64]
// (R8/R10-proven zero-conflict geometry, slot=chunk^(row&7)).
// zn pre-scaled -> epilogue = bare exp2. Interior tiles (bj != T-1) skip all
// masking (pads only live in the last panel). NO memset needed: fold reads
// exactly the written slots. Row-partials -> slot 4*bj+wcol; col-partials
// (symmetry) -> slot 4T + 2*bi + wrow.
// ---------------------------------------------------------------------------
__global__ __launch_bounds__(512) void gram_mfma(const short* __restrict__ znb,
                                                 float* __restrict__ P2d, int n,
                                                 int T, int nwg, int Npad) {
    __shared__ short As[2][128 * 64];
    __shared__ short Bs[2][128 * 64];

    int b = blockIdx.x;
    int q = nwg >> 3, r8 = nwg & 7, xc = b & 7, oo = b >> 3;
    int sid = (xc < r8 ? xc * (q + 1) : r8 * (q + 1) + (xc - r8) * q) + oo;
    int bi = 0, rem = sid;
    while (rem >= T - bi) { rem -= T - bi; ++bi; }
    int bj = bi + rem;
    int i0 = bi * 128, j0 = bj * 128;

    int t    = threadIdx.x;
    int lane = t & 63;
    int wid  = t >> 6;              // 0..7
    int wrow = wid >> 2, wcol = wid & 3;
    int l15  = lane & 15, lg = lane >> 4;
    int srow = lane >> 3;           // 0..7
    int sch  = lane & 7;            // 0..7

    f32x4 acc[4][2];
#pragma unroll
    for (int m = 0; m < 4; ++m)
#pragma unroll
        for (int nn = 0; nn < 2; ++nn)
#pragma unroll
            for (int r = 0; r < 4; ++r) acc[m][nn][r] = 0.f;

    bf16x8 sa[2][2], sb[2][2];
    // prologue: stage kt=0 (k 0..127 = 2 slabs of 64); each thread 2 rows/slab
#pragma unroll
    for (int sl = 0; sl < 2; ++sl)
#pragma unroll
        for (int s = 0; s < 2; ++s) {
            int row = wid * 16 + s * 8 + srow;
            int gch = sch ^ (row & 7);
            sa[sl][s] = *(const bf16x8*)(znb + (size_t)(i0 + row) * NN_HID + sl * 64 + gch * 8);
            sb[sl][s] = *(const bf16x8*)(znb + (size_t)(j0 + row) * NN_HID + sl * 64 + gch * 8);
        }

#pragma unroll
    for (int kt = 0; kt < 2; ++kt) {
#pragma unroll
        for (int sl = 0; sl < 2; ++sl)
#pragma unroll
            for (int s = 0; s < 2; ++s) {
                int row = wid * 16 + s * 8 + srow;
                *(bf16x8*)(&As[sl][row * 64 + sch * 8]) = sa[sl][s];
                *(bf16x8*)(&Bs[sl][row * 64 + sch * 8]) = sb[sl][s];
            }
        __syncthreads();
        if (kt == 0) {
            // issue kt=1 global loads (k 128..255), overlap with compute below
#pragma unroll
            for (int sl = 0; sl < 2; ++sl)
#pragma unroll
                for (int s = 0; s < 2; ++s) {
                    int row = wid * 16 + s * 8 + srow;
                    int gch = sch ^ (row & 7);
                    sa[sl][s] = *(const bf16x8*)(znb + (size_t)(i0 + row) * NN_HID + 128 + sl * 64 + gch * 8);
                    sb[sl][s] = *(const bf16x8*)(znb + (size_t)(j0 + row) * NN_HID + 128 + sl * 64 + gch * 8);
                }
        }
#pragma unroll
        for (int sl = 0; sl < 2; ++sl) {
#pragma unroll
            for (int ks = 0; ks < 2; ++ks) {
                bf16x8 av[4], bv[2];
#pragma unroll
                for (int m = 0; m < 4; ++m) {
                    int Ra = wrow * 64 + m * 16 + l15;
                    int ca = (ks * 4 + lg) ^ (Ra & 7);
                    av[m] = *(const bf16x8*)(&As[sl][Ra * 64 + ca * 8]);
                }
#pragma unroll
                for (int nn = 0; nn < 2; ++nn) {
                    int Rb = wcol * 32 + nn * 16 + l15;
                    int cb = (ks * 4 + lg) ^ (Rb & 7);
                    bv[nn] = *(const bf16x8*)(&Bs[sl][Rb * 64 + cb * 8]);
                }
#pragma unroll
                for (int m = 0; m < 4; ++m)
#pragma unroll
                    for (int nn = 0; nn < 2; ++nn)
                        acc[m][nn] = __builtin_amdgcn_mfma_f32_16x16x32_bf16(av[m], bv[nn], acc[m][nn], 0, 0, 0);
            }
        }
        if (kt == 0) __syncthreads();
    }

    // epilogue: bare exp2 (zn pre-scaled); mask only in the last panel
    int i0w = i0 + wrow * 64;
    int j0w = j0 + wcol * 32;
    bool diag = (bj == bi);
    if (bj == T - 1) {
#pragma unroll
        for (int m = 0; m < 4; ++m)
#pragma unroll
            for (int nn = 0; nn < 2; ++nn) {
                int gj = j0w + nn * 16 + l15;
                bool jok = gj < n;
#pragma unroll
                for (int r = 0; r < 4; ++r) {
                    int gi = i0w + m * 16 + lg * 4 + r;
                    acc[m][nn][r] = (jok && gi < n) ? __builtin_exp2f(acc[m][nn][r]) : 0.f;
                }
            }
    } else {
#pragma unroll
        for (int m = 0; m < 4; ++m)
#pragma unroll
            for (int nn = 0; nn < 2; ++nn)
#pragma unroll
                for (int r = 0; r < 4; ++r)
                    acc[m][nn][r] = __builtin_exp2f(acc[m][nn][r]);
    }
    float* rowslot = P2d + (size_t)(4 * bj + wcol) * Npad;
#pragma unroll
    for (int m = 0; m < 4; ++m) {
#pragma unroll
        for (int r = 0; r < 4; ++r) {
            float v = acc[m][0][r] + acc[m][1][r];
            v += __shfl_xor(v, 1, 64);
            v += __shfl_xor(v, 2, 64);
            v += __shfl_xor(v, 4, 64);
            v += __shfl_xor(v, 8, 64);
            if (l15 == 0) {
                int gi = i0w + m * 16 + lg * 4 + r;
                if (gi < n) rowslot[gi] = v;
            }
        }
    }
    if (!diag) {
        float* colslot = P2d + (size_t)(4 * T + 2 * bi + wrow) * Npad;
#pragma unroll
        for (int nn = 0; nn < 2; ++nn) {
            float v = 0.f;
#pragma unroll
            for (int m = 0; m < 4; ++m)
#pragma unroll
                for (int r = 0; r < 4; ++r) v += acc[m][nn][r];
            v += __shfl_xor(v, 16, 64);
            v += __shfl_xor(v, 32, 64);
            if (lg == 0) {
                int gj = j0w + nn * 16 + l15;
                if (gj < n) colslot[gj] = v;
            }
        }
    }
}

// ---------------------------------------------------------------------------
// Fold: R[i] = sum over exactly the slots gram wrote for node i (panel p):
//   row slots 4*bj+wc for bj in [p,T), col slots 4T+2*bi+wr for bi in [0,p).
// No P2d zero-fill needed.
// ---------------------------------------------------------------------------
__global__ void fold_kernel(const float* __restrict__ P2d, float* __restrict__ R,
                            int n, int T, int Npad) {
    int i = blockIdx.x * 256 + threadIdx.x;
    if (i >= n) return;
    int p = i >> 7;
    const float* base = P2d + i;
    float s = 0.f;
    for (int bj = p; bj < T; ++bj) {
        const float* qq = base + (size_t)(4 * bj) * Npad;
        s += qq[0] + qq[(size_t)Npad] + qq[(size_t)2 * Npad] + qq[(size_t)3 * Npad];
    }
    const float* c0 = base + (size_t)(4 * T) * Npad;
    for (int bi = 0; bi < p; ++bi) {
        s += c0[(size_t)(2 * bi) * Npad] + c0[(size_t)(2 * bi + 1) * Npad];
    }
    R[i] = s;
}

__global__ void loss_kernel(const float* __restrict__ R, const float* __restrict__ dvec,
                            float* __restrict__ out_loss, int n) {
    __shared__ float s[1024];
    int t = threadIdx.x;
    float sum = 0.f;
    for (int i = t; i < n; i += 1024) {
        float d   = dvec[i];
        float off = R[i] - d;
        sum += -logf(d / (off + off));
    }
    s[t] = sum;
    __syncthreads();
    for (int o = 512; o > 0; o >>= 1) {
        if (t < o) s[t] += s[t + o];
        __syncthreads();
    }
    if (t == 0) *out_loss = s[0] / n;
}

// ---------------------------------------------------------------------------
extern "C" void kernel_launch(void* const* d_in, const int* in_sizes, int n_in,
                              void* d_out, int out_size, void* d_ws, size_t ws_size,
                              hipStream_t stream) {
    const float* x   = (const float*)d_in[0];
    const int*   src = (const int*)d_in[1];
    const int*   dst = (const int*)d_in[2];
    const float* W0  = (const float*)d_in[3];
    const float* a0s = (const float*)d_in[4];
    const float* a0d = (const float*)d_in[5];
    const float* W1  = (const float*)d_in[6];
    const float* a1s = (const float*)d_in[7];
    const float* a1d = (const float*)d_in[8];
    const float* W2  = (const float*)d_in[9];
    const float* a2s = (const float*)d_in[10];
    const float* a2d = (const float*)d_in[11];
    const float* Wout= (const float*)d_in[12];
    const float* aos = (const float*)d_in[13];
    const float* aod = (const float*)d_in[14];

    int N = in_sizes[0] / NN_F_IN;
    int E = in_sizes[1];
    int Npad = ((N + 127) / 128) * 128;
    int T = Npad / 128;
    int nwg = T * (T + 1) / 2;
    float* out = (float*)d_out;

    char*  ws  = (char*)d_ws;
    size_t off = 0;
    auto alloc = [&](size_t bytes) -> void* {
        void* p = ws + off;
        off += bytes;
        off = (off + 255) & ~(size_t)255;
        return p;
    };
    size_t hbBytes = (size_t)N * 320 * 2;
    size_t znBytes = (size_t)Npad * NN_HID * 2;
    unsigned short* Hb = (unsigned short*)alloc(hbBytes > znBytes ? hbBytes : znBytes);
    short* znb = (short*)Hb;  // alias: znb live only between rownorm and gram
    unsigned short* Bl = (unsigned short*)alloc((size_t)N * NN_HID * 2);
    unsigned short* Bc = (unsigned short*)alloc((size_t)N * NN_HID * 2);
    size_t xbBytes = (size_t)N * NN_F_IN * 2;
    size_t p2Bytes = (size_t)6 * T * Npad * 4;   // 4T row slots + 2T col slots
    void* XbP2d = alloc(xbBytes > p2Bytes ? xbBytes : p2Bytes);
    unsigned short* Xb  = (unsigned short*)XbP2d;  // live: prep..fc L0
    float*          P2d = (float*)XbP2d;           // live: gram..fold
    unsigned short* Wt0 = (unsigned short*)alloc((size_t)256 * 512 * 2);
    unsigned short* Wt1 = (unsigned short*)alloc((size_t)256 * 256 * 2);
    unsigned short* Wt2 = (unsigned short*)alloc((size_t)256 * 256 * 2);
    unsigned short* Wto = (unsigned short*)alloc((size_t)384 * 256 * 2);
    float* es     = (float*)alloc((size_t)N * NN_HEADS * 4);
    float* ed     = (float*)alloc((size_t)N * NN_HEADS * 4);
    float* wC     = (float*)alloc((size_t)E * NN_HEADS * 4);
    float* zinvA  = (float*)alloc((size_t)N * NN_HEADS * 4);
    float* Rrow   = (float*)alloc((size_t)N * 4);
    float* dvec   = (float*)alloc((size_t)N * 4);
    int*   counts = (int*)alloc((size_t)N * 4);
    int*   rs     = (int*)alloc((size_t)(N + 1) * 4);
    int*   cursor = (int*)alloc((size_t)N * 4);
    int*   csr    = (int*)alloc((size_t)E * 4);

    // ---- CSR build
    hipMemsetAsync(counts, 0, (size_t)N * 4, stream);
    count_kernel<<<(E + 255) / 256, 256, 0, stream>>>(dst, counts, E);
    scan_kernel<<<1, 1024, 0, stream>>>(counts, rs, cursor, N);
    scatter_kernel<<<(E + 255) / 256, 256, 0, stream>>>(src, dst, cursor, csr, E);

    // ---- fused prep (X + 4 W casts)
    int n4X = N * NN_F_IN / 4;
    int prepTotal = n4X + 256 * 512 + 256 * 256 + 256 * 256 + 384 * 256;
    prep_kernel<<<(prepTotal + 255) / 256, 256, 0, stream>>>(
        x, W0, W1, W2, Wout, Xb, Wt0, Wt1, Wt2, Wto, n4X);

    int atGrid = (N * NN_HEADS + 255) / 256;
    int ghGrid = (N + 3) / 4;
    int mT64 = (N + 63) / 64;

    // ---- layer 0: Xb -> Hb -> Bl
    fc_mfma<<<dim3(4, mT64), 256, 0, stream>>>(Xb, Wt0, Hb, N, 512, 256, 256);
    attn_kernel<<<atGrid, 256, 0, stream>>>(Hb, a0s, a0d, es, ed, N, NN_FH);
    edge_wz<<<ghGrid, 256, 0, stream>>>(es, ed, csr, rs, wC, zinvA, N);
    gather_hidden<<<ghGrid, 256, 0, stream>>>(Hb, wC, zinvA, csr, rs, nullptr, Bl, N, -1.f);

    // ---- layer 1: Bl -> Hb -> Bc (beta = 0.5/3)
    fc_mfma<<<dim3(4, mT64), 256, 0, stream>>>(Bl, Wt1, Hb, N, 256, 256, 256);
    attn_kernel<<<atGrid, 256, 0, stream>>>(Hb, a1s, a1d, es, ed, N, NN_FH);
    edge_wz<<<ghGrid, 256, 0, stream>>>(es, ed, csr, rs, wC, zinvA, N);
    gather_hidden<<<ghGrid, 256, 0, stream>>>(Hb, wC, zinvA, csr, rs, Bl, Bc, N, LAMDA_F / 3.f);

    // ---- layer 2: Bc -> Hb -> Bl (beta = 0.5/4)
    fc_mfma<<<dim3(4, mT64), 256, 0, stream>>>(Bc, Wt2, Hb, N, 256, 256, 256);
    attn_kernel<<<atGrid, 256, 0, stream>>>(Hb, a2s, a2d, es, ed, N, NN_FH);
    edge_wz<<<ghGrid, 256, 0, stream>>>(es, ed, csr, rs, wC, zinvA, N);
    gather_hidden<<<ghGrid, 256, 0, stream>>>(Hb, wC, zinvA, csr, rs, Bc, Bl, N, LAMDA_F / 4.f);

    // ---- bind_loss(Bl): znb (aliases Hb, pad rows zeroed in rownorm)
    rownorm_kernel<<<Npad, 256, 0, stream>>>(Bl, znb, dvec, N);
    gram_mfma<<<nwg, 512, 0, stream>>>(znb, P2d, N, T, nwg, Npad);
    fold_kernel<<<(N + 255) / 256, 256, 0, stream>>>(P2d, Rrow, N, T, Npad);
    loss_kernel<<<1, 1024, 0, stream>>>(Rrow, dvec, out + (size_t)N * NN_NCLASS, N);

    // ---- output layer: Bl -> Hb(320) -> d_out
    fc_mfma<<<dim3(5, mT64), 256, 0, stream>>>(Bl, Wto, Hb, N, 256, 320, 320);
    attn_kernel<<<atGrid, 256, 0, stream>>>(Hb, aos, aod, es, ed, N, NN_NCLASS);
    edge_wz<<<ghGrid, 256, 0, stream>>>(es, ed, csr, rs, wC, zinvA, N);
    gather_final<<<N, NN_HEADS * NN_NCLASS, 0, stream>>>(Hb, wC, zinvA, csr, rs, out, N);
}

// Round 12
// 384.786 us; speedup vs baseline: 1.0880x; 1.0880x over previous
//
#include <hip/hip_runtime.h>
#include <hip/hip_bf16.h>
#include <math.h>

#define NN_F_IN   512
#define NN_HID    256
#define NN_HEADS  8
#define NN_FH     32
#define NN_NCLASS 40
#define TAU_F     0.5f
#define LAMDA_F   0.5f
// sqrt(2 * log2(e)) : makes gram epilogue a bare exp2
#define ZN_SCALE  1.6986436f

typedef __attribute__((ext_vector_type(8))) short bf16x8;
typedef __attribute__((ext_vector_type(4))) float f32x4;

typedef __attribute__((address_space(1))) unsigned int gu32_t;
typedef __attribute__((address_space(3))) unsigned int lu32_t;

static __device__ __forceinline__ float lrelu02(float x) { return x >= 0.f ? x : 0.2f * x; }
static __device__ __forceinline__ float elu1(float x)    { return x > 0.f ? x : expm1f(x); }
static __device__ __forceinline__ float b2f(unsigned short u) {
    unsigned int x = ((unsigned int)u) << 16;
    return __uint_as_float(x);
}
static __device__ __forceinline__ unsigned short f2b(float f) {
    __hip_bfloat16 hb = __float2bfloat16(f);
    return *reinterpret_cast<unsigned short*>(&hb);
}

// ---------------------------------------------------------------------------
// Fused prep: X cast (float4-wide) + 4 transposed W casts, one launch.
// ---------------------------------------------------------------------------
__global__ void prep_kernel(const float* __restrict__ x,
                            const float* __restrict__ W0, const float* __restrict__ W1,
                            const float* __restrict__ W2, const float* __restrict__ Wo,
                            unsigned short* __restrict__ Xb,
                            unsigned short* __restrict__ Wt0, unsigned short* __restrict__ Wt1,
                            unsigned short* __restrict__ Wt2, unsigned short* __restrict__ Wto,
                            int n4X) {
    int i = blockIdx.x * 256 + threadIdx.x;
    if (i < n4X) {
        float4 v = *(const float4*)(x + (size_t)i * 4);
        ushort4 o;
        o.x = f2b(v.x); o.y = f2b(v.y); o.z = f2b(v.z); o.w = f2b(v.w);
        *(ushort4*)(Xb + (size_t)i * 4) = o;
        return;
    }
    i -= n4X;
    if (i < 256 * 512) {            // Wt0: Np=256, K=512, Nc=256
        int np = i >> 9, k = i & 511;
        Wt0[i] = f2b(W0[(size_t)k * 256 + np]);
        return;
    }
    i -= 256 * 512;
    if (i < 256 * 256) {            // Wt1
        int np = i >> 8, k = i & 255;
        Wt1[i] = f2b(W1[(size_t)k * 256 + np]);
        return;
    }
    i -= 256 * 256;
    if (i < 256 * 256) {            // Wt2
        int np = i >> 8, k = i & 255;
        Wt2[i] = f2b(W2[(size_t)k * 256 + np]);
        return;
    }
    i -= 256 * 256;
    if (i < 384 * 256) {            // Wto: Np=384, K=256, Nc=320
        int np = i >> 8, k = i & 255;
        Wto[i] = f2b(np < 320 ? Wo[(size_t)k * 320 + np] : 0.f);
    }
}

// ---------------------------------------------------------------------------
// MFMA GEMM: H[m][col] = sum_k A[m][k] * B[col][k], A/B bf16, H bf16.
// Block = 4 waves 2x2 -> 64x64 tile; wave = 32x32 = 2x2 frags of 16x16x32.
// ---------------------------------------------------------------------------
__global__ __launch_bounds__(256) void fc_mfma(const unsigned short* __restrict__ A,
                                               const unsigned short* __restrict__ B,
                                               unsigned short* __restrict__ H,
                                               int M, int K, int ncols, int ldH) {
    int t = threadIdx.x, lane = t & 63, wid = t >> 6;
    int wrow = wid >> 1, wcol = wid & 1;
    int l15 = lane & 15, lg = lane >> 4;
    int mbase = blockIdx.y * 64 + wrow * 32;
    int nbase = blockIdx.x * 64 + wcol * 32;

    const unsigned short* Ap[2];
    const unsigned short* Bp[2];
#pragma unroll
    for (int m = 0; m < 2; ++m) {
        int rr = mbase + m * 16 + l15;
        if (rr > M - 1) rr = M - 1;
        Ap[m] = A + (size_t)rr * K + lg * 8;
        Bp[m] = B + (size_t)(nbase + m * 16 + l15) * K + lg * 8;
    }
    f32x4 acc[2][2];
#pragma unroll
    for (int m = 0; m < 2; ++m)
#pragma unroll
        for (int nn = 0; nn < 2; ++nn)
#pragma unroll
            for (int r = 0; r < 4; ++r) acc[m][nn][r] = 0.f;

    bf16x8 aP[2], bP[2], aQ[2], bQ[2];
#pragma unroll
    for (int m = 0; m < 2; ++m) {
        aP[m] = *(const bf16x8*)(Ap[m]);
        bP[m] = *(const bf16x8*)(Bp[m]);
    }
    int nhalf = K >> 6;
    int kk = 32;
    for (int it = 0; it < nhalf; ++it) {
#pragma unroll
        for (int m = 0; m < 2; ++m) {
            aQ[m] = *(const bf16x8*)(Ap[m] + kk);
            bQ[m] = *(const bf16x8*)(Bp[m] + kk);
        }
#pragma unroll
        for (int m = 0; m < 2; ++m)
#pragma unroll
            for (int nn = 0; nn < 2; ++nn)
                acc[m][nn] = __builtin_amdgcn_mfma_f32_16x16x32_bf16(aP[m], bP[nn], acc[m][nn], 0, 0, 0);
        if (it + 1 < nhalf) {
#pragma unroll
            for (int m = 0; m < 2; ++m) {
                aP[m] = *(const bf16x8*)(Ap[m] + kk + 32);
                bP[m] = *(const bf16x8*)(Bp[m] + kk + 32);
            }
        }
#pragma unroll
        for (int m = 0; m < 2; ++m)
#pragma unroll
            for (int nn = 0; nn < 2; ++nn)
                acc[m][nn] = __builtin_amdgcn_mfma_f32_16x16x32_bf16(aQ[m], bQ[nn], acc[m][nn], 0, 0, 0);
        kk += 64;
    }
#pragma unroll
    for (int m = 0; m < 2; ++m) {
#pragma unroll
        for (int nn = 0; nn < 2; ++nn) {
            int col = nbase + nn * 16 + l15;
            if (col >= ncols) continue;
#pragma unroll
            for (int r = 0; r < 4; ++r) {
                int row = mbase + m * 16 + lg * 4 + r;
                if (row < M) H[(size_t)row * ldH + col] = f2b(acc[m][nn][r]);
            }
        }
    }
}

// ---------------------------------------------------------------------------
// es/ed dot products (Hm bf16)
// ---------------------------------------------------------------------------
__global__ void attn_kernel(const unsigned short* __restrict__ Hm, const float* __restrict__ As,
                            const float* __restrict__ Ad, float* __restrict__ es,
                            float* __restrict__ ed, int n, int df) {
    int idx = blockIdx.x * blockDim.x + threadIdx.x;
    if (idx >= n * NN_HEADS) return;
    int nn = idx / NN_HEADS, hh = idx - nn * NN_HEADS;
    const unsigned short* hp = Hm + (size_t)nn * NN_HEADS * df + hh * df;
    const float* ap = As + hh * df;
    const float* bp = Ad + hh * df;
    float s1 = 0.f, s2 = 0.f;
    for (int d = 0; d < df; d += 4) {
        ushort4 hv = *(const ushort4*)(hp + d);
        float4 av = *(const float4*)(ap + d);
        float4 bv = *(const float4*)(bp + d);
        float h0 = b2f(hv.x), h1 = b2f(hv.y), h2 = b2f(hv.z), h3 = b2f(hv.w);
        s1 += h0 * av.x + h1 * av.y + h2 * av.z + h3 * av.w;
        s2 += h0 * bv.x + h1 * bv.y + h2 * bv.z + h3 * bv.w;
    }
    es[idx] = s1;
    ed[idx] = s2;
}

// ---------------------------------------------------------------------------
// Edge weights (FINAL LAYER ONLY — 40x redundancy there justifies the pass).
// ---------------------------------------------------------------------------
__global__ __launch_bounds__(256) void edge_wz(
    const float* __restrict__ es, const float* __restrict__ ed,
    const int* __restrict__ csr_src, const int* __restrict__ row_start,
    float* __restrict__ wC, float* __restrict__ zinv, int n) {
    int lane = threadIdx.x & 63;
    int nn   = blockIdx.x * 4 + (threadIdx.x >> 6);
    if (nn >= n) return;
    int s0 = row_start[nn], s1 = row_start[nn + 1];
    int h    = lane & 7;
    int slot = lane >> 3;
    float edh = ed[nn * NN_HEADS + h];
    float z = 0.f;
    for (int e = s0 + slot; e < s1; e += 8) {
        int sv = csr_src[e];
        float w = __expf(lrelu02(es[sv * NN_HEADS + h] + edh));
        wC[(size_t)e * NN_HEADS + h] = w;
        z += w;
    }
    z += __shfl_xor(z, 8, 64);
    z += __shfl_xor(z, 16, 64);
    z += __shfl_xor(z, 32, 64);
    if (slot == 0) zinv[nn * NN_HEADS + h] = 1.f / z;
}

// ---------------------------------------------------------------------------
// CSR build
// ---------------------------------------------------------------------------
__global__ void count_kernel(const int* __restrict__ dst, int* __restrict__ counts, int E) {
    int e = blockIdx.x * blockDim.x + threadIdx.x;
    if (e < E) atomicAdd(&counts[dst[e]], 1);
}

__global__ void scan_kernel(const int* __restrict__ counts, int* __restrict__ row_start,
                            int* __restrict__ cursor, int n) {
    __shared__ int s[1024];
    int t  = threadIdx.x;
    int ch = (n + 1023) / 1024;
    int lo = t * ch;
    int sum = 0;
    for (int j = 0; j < ch; ++j) {
        int i = lo + j;
        if (i < n) sum += counts[i];
    }
    s[t] = sum;
    __syncthreads();
    for (int off = 1; off < 1024; off <<= 1) {
        int v = 0;
        if (t >= off) v = s[t - off];
        __syncthreads();
        s[t] += v;
        __syncthreads();
    }
    int run = (t == 0) ? 0 : s[t - 1];
    for (int j = 0; j < ch; ++j) {
        int i = lo + j;
        if (i < n) {
            row_start[i] = run;
            cursor[i] = run;
            run += counts[i];
        }
    }
    if (t == 1023) row_start[n] = s[1023];
}

__global__ void scatter_kernel(const int* __restrict__ src, const int* __restrict__ dst,
                               int* __restrict__ cursor, int* __restrict__ csr_src, int E) {
    int e = blockIdx.x * blockDim.x + threadIdx.x;
    if (e < E) {
        int d   = dst[e];
        int pos = atomicAdd(&cursor[d], 1);
        csr_src[pos] = src[e];
    }
}

// ---------------------------------------------------------------------------
// Hidden-layer gather, FUSED edge-weight compute (one __expf per edge per
// 8-lane head group — 8x redundant but ~4cy each; kills the wC round trip
// and the separate edge_wz pass). Guard-free batches + tail.
// ---------------------------------------------------------------------------
__global__ __launch_bounds__(256) void gather_hidden(
    const unsigned short* __restrict__ Hm, const float* __restrict__ es,
    const float* __restrict__ ed, const int* __restrict__ csr_src,
    const int* __restrict__ row_start, const unsigned short* __restrict__ last,
    unsigned short* __restrict__ out, int n, float beta) {
    int lane = threadIdx.x & 63;
    int nn   = blockIdx.x * 4 + (threadIdx.x >> 6);
    if (nn >= n) return;
    int s0 = row_start[nn], s1 = row_start[nn + 1];
    int h2 = lane >> 3;
    float edh = ed[nn * NN_HEADS + h2];

    float zacc = 0.f;
    float a0 = 0.f, a1 = 0.f, a2 = 0.f, a3 = 0.f;
    int fullEnd = s0 + ((s1 - s0) & ~7);
    int e = s0;
    for (; e < fullEnd; e += 8) {
        int idx[8];
        float q[8];
#pragma unroll
        for (int j = 0; j < 8; ++j) idx[j] = csr_src[e + j];
#pragma unroll
        for (int j = 0; j < 8; ++j) q[j] = es[idx[j] * NN_HEADS + h2];
        ushort4 r[8];
#pragma unroll
        for (int j = 0; j < 8; ++j) r[j] = *(const ushort4*)&Hm[(size_t)idx[j] * NN_HID + lane * 4];
#pragma unroll
        for (int j = 0; j < 8; ++j) {
            float w = __expf(lrelu02(q[j] + edh));
            zacc += w;
            a0 += w * b2f(r[j].x); a1 += w * b2f(r[j].y);
            a2 += w * b2f(r[j].z); a3 += w * b2f(r[j].w);
        }
    }
    if (e < s1) {
        int c = s1 - e;
        int idx[8];
        float q[8];
#pragma unroll
        for (int j = 0; j < 8; ++j) idx[j] = csr_src[(j < c) ? e + j : e];
#pragma unroll
        for (int j = 0; j < 8; ++j) q[j] = es[idx[j] * NN_HEADS + h2];
        ushort4 r[8];
#pragma unroll
        for (int j = 0; j < 8; ++j) r[j] = *(const ushort4*)&Hm[(size_t)idx[j] * NN_HID + lane * 4];
#pragma unroll
        for (int j = 0; j < 8; ++j) {
            if (j < c) {
                float w = __expf(lrelu02(q[j] + edh));
                zacc += w;
                a0 += w * b2f(r[j].x); a1 += w * b2f(r[j].y);
                a2 += w * b2f(r[j].z); a3 += w * b2f(r[j].w);
            }
        }
    }
    float zi = 1.f / zacc;
    float v0 = elu1(a0 * zi), v1 = elu1(a1 * zi), v2 = elu1(a2 * zi), v3 = elu1(a3 * zi);
    if (beta >= 0.f) {
        ushort4 lv = *(const ushort4*)&last[(size_t)nn * NN_HID + lane * 4];
        v0 = beta * b2f(lv.x) + (1.f - beta) * v0;
        v1 = beta * b2f(lv.y) + (1.f - beta) * v1;
        v2 = beta * b2f(lv.z) + (1.f - beta) * v2;
        v3 = beta * b2f(lv.w) + (1.f - beta) * v3;
    }
    ushort4 o;
    o.x = f2b(v0); o.y = f2b(v1); o.z = f2b(v2); o.w = f2b(v3);
    *(ushort4*)&out[(size_t)nn * NN_HID + lane * 4] = o;
}

// ---------------------------------------------------------------------------
// Final layer gather: weighted sum + head-mean + log_softmax -> d_out
// ---------------------------------------------------------------------------
__global__ void gather_final(const unsigned short* __restrict__ Hm, const float* __restrict__ wC,
                             const float* __restrict__ zinv, const int* __restrict__ csr_src,
                             const int* __restrict__ row_start, float* __restrict__ dout, int n) {
    int nn = blockIdx.x;
    __shared__ float accs[NN_HEADS * NN_NCLASS];
    int t = threadIdx.x;  // 0..319
    int s0 = row_start[nn], s1 = row_start[nn + 1];
    int hh = t / NN_NCLASS;
    float acc = 0.f;
    const int LD = NN_HEADS * NN_NCLASS;
    int fullEnd = s0 + ((s1 - s0) & ~7);
    int e = s0;
    for (; e < fullEnd; e += 8) {
        int idx[8];
        float wv[8];
#pragma unroll
        for (int j = 0; j < 8; ++j) {
            idx[j] = csr_src[e + j];
            wv[j]  = wC[(size_t)(e + j) * NN_HEADS + hh];
        }
        float v[8];
#pragma unroll
        for (int j = 0; j < 8; ++j) v[j] = b2f(Hm[(size_t)idx[j] * LD + t]);
#pragma unroll
        for (int j = 0; j < 8; ++j) acc += wv[j] * v[j];
    }
    if (e < s1) {
        int c = s1 - e;
        int idx[8];
        float wv[8];
#pragma unroll
        for (int j = 0; j < 8; ++j) {
            int p = (j < c) ? e + j : e;
            idx[j] = csr_src[p];
            wv[j]  = wC[(size_t)p * NN_HEADS + hh];
        }
        float v[8];
#pragma unroll
        for (int j = 0; j < 8; ++j) v[j] = b2f(Hm[(size_t)idx[j] * LD + t]);
#pragma unroll
        for (int j = 0; j < 8; ++j) {
            if (j < c) acc += wv[j] * v[j];
        }
    }
    accs[t] = acc * zinv[nn * NN_HEADS + hh];
    __syncthreads();
    if (t < 64) {
        float v = -INFINITY;
        if (t < NN_NCLASS) {
            float sacc = 0.f;
#pragma unroll
            for (int h2 = 0; h2 < NN_HEADS; ++h2) sacc += accs[h2 * NN_NCLASS + t];
            v = sacc * (1.f / NN_HEADS);
        }
        float mx = v;
#pragma unroll
        for (int o = 1; o < 64; o <<= 1) mx = fmaxf(mx, __shfl_xor(mx, o, 64));
        float ex = (t < NN_NCLASS) ? expf(v - mx) : 0.f;
        float se = ex;
#pragma unroll
        for (int o = 1; o < 64; o <<= 1) se += __shfl_xor(se, o, 64);
        if (t < NN_NCLASS) dout[(size_t)nn * NN_NCLASS + t] = (v - mx) - logf(se);
    }
}

// ---------------------------------------------------------------------------
// Row-normalize + SCALED bf16 zn (pre-mult by sqrt(2*log2e)) + diagonal.
// Grid = Npad blocks: pad rows zero-filled here.
// ---------------------------------------------------------------------------
__global__ void rownorm_kernel(const unsigned short* __restrict__ z, short* __restrict__ znb,
                               float* __restrict__ dvec, int n) {
    int nn = blockIdx.x;
    int t  = threadIdx.x;  // 256
    if (nn >= n) {
        znb[(size_t)nn * NN_HID + t] = 0;
        return;
    }
    float v  = b2f(z[(size_t)nn * NN_HID + t]);
    float sq = v * v;
#pragma unroll
    for (int o = 1; o < 64; o <<= 1) sq += __shfl_xor(sq, o, 64);
    __shared__ float ws[4];
    if ((t & 63) == 0) ws[t >> 6] = sq;
    __syncthreads();
    float s = ws[0] + ws[1] + ws[2] + ws[3];
    float m = fmaxf(sqrtf(s), 1e-12f);
    znb[(size_t)nn * NN_HID + t] = (short)f2b((v / m) * ZN_SCALE);
    if (t == 0) dvec[nn] = __expf((s / (m * m)) * (1.f / TAU_F));
}

// ---------------------------------------------------------------------------
// Symmetric gram rowsums — m97-style: 4 waves, 128x128 tile, BK=32, 8-step
// K-loop, single-buffered 16KB LDS staged via global_load_lds width=16
// (direct HBM/L2 -> LDS DMA, no VGPR roundtrip). LDS [row][32] linear;
// bank balance via 2-bit chunk XOR (slot = kc ^ ((row>>1)&3)) applied to
// BOTH the pre-swizzled global source and the ds_read (rule #21).
// Epilogue: bare exp2 (zn pre-scaled), interior fast path, R10 slot scheme:
//   row-partials -> slot 2*bj+wcol ; col-partials -> slot 2*bi+wrow.
// Every slot [0,2T) is written for every node -> fold is a plain sum.
// ---------------------------------------------------------------------------
__global__ __launch_bounds__(256) void gram_mfma(const short* __restrict__ znb,
                                                 float* __restrict__ P2d, int n,
                                                 int T, int nwg, int Npad) {
    __shared__ short As[128 * 32];
    __shared__ short Bs[128 * 32];

    int b = blockIdx.x;
    int q = nwg >> 3, r8 = nwg & 7, xc = b & 7, oo = b >> 3;
    int sid = (xc < r8 ? xc * (q + 1) : r8 * (q + 1) + (xc - r8) * q) + oo;
    int bi = 0, rem = sid;
    while (rem >= T - bi) { rem -= T - bi; ++bi; }
    int bj = bi + rem;
    int i0 = bi * 128, j0 = bj * 128;

    int t    = threadIdx.x;
    int lane = t & 63;
    int wid  = t >> 6;
    int wrow = wid >> 1, wcol = wid & 1;
    int l15  = lane & 15, lg = lane >> 4;

    // staging: wave covers chunks 2*wid and 2*wid+1; chunk = 16 rows x 32 k.
    int srow0 = 16 * (2 * wid + 0) + (lane >> 2);
    int srow1 = 16 * (2 * wid + 1) + (lane >> 2);
    int kc    = lane & 3;
    int kc0   = kc ^ ((srow0 >> 1) & 3);   // pre-swizzled source chunk
    int kc1   = kc ^ ((srow1 >> 1) & 3);
    const short* gA0 = znb + (size_t)(i0 + srow0) * NN_HID + kc0 * 8;
    const short* gA1 = znb + (size_t)(i0 + srow1) * NN_HID + kc1 * 8;
    const short* gB0 = znb + (size_t)(j0 + srow0) * NN_HID + kc0 * 8;
    const short* gB1 = znb + (size_t)(j0 + srow1) * NN_HID + kc1 * 8;
    short* lA0 = As + (2 * wid + 0) * 512 + lane * 8;   // wave-linear dest
    short* lA1 = As + (2 * wid + 1) * 512 + lane * 8;
    short* lB0 = Bs + (2 * wid + 0) * 512 + lane * 8;
    short* lB1 = Bs + (2 * wid + 1) * 512 + lane * 8;

    f32x4 acc[4][4];
#pragma unroll
    for (int m = 0; m < 4; ++m)
#pragma unroll
        for (int nn = 0; nn < 4; ++nn)
#pragma unroll
            for (int r = 0; r < 4; ++r) acc[m][nn][r] = 0.f;

#pragma unroll
    for (int s = 0; s < 8; ++s) {
        int ko = s * 32;
        __builtin_amdgcn_global_load_lds((gu32_t*)(gA0 + ko), (lu32_t*)lA0, 16, 0, 0);
        __builtin_amdgcn_global_load_lds((gu32_t*)(gA1 + ko), (lu32_t*)lA1, 16, 0, 0);
        __builtin_amdgcn_global_load_lds((gu32_t*)(gB0 + ko), (lu32_t*)lB0, 16, 0, 0);
        __builtin_amdgcn_global_load_lds((gu32_t*)(gB1 + ko), (lu32_t*)lB1, 16, 0, 0);
        __syncthreads();
        bf16x8 av[4], bv[4];
#pragma unroll
        for (int m = 0; m < 4; ++m) {
            int Ra = wrow * 64 + m * 16 + l15;
            int ca = lg ^ ((Ra >> 1) & 3);
            av[m] = *(const bf16x8*)&As[Ra * 32 + ca * 8];
        }
#pragma unroll
        for (int m = 0; m < 4; ++m) {
            int Rb = wcol * 64 + m * 16 + l15;
            int cb = lg ^ ((Rb >> 1) & 3);
            bv[m] = *(const bf16x8*)&Bs[Rb * 32 + cb * 8];
        }
#pragma unroll
        for (int m = 0; m < 4; ++m)
#pragma unroll
            for (int nn = 0; nn < 4; ++nn)
                acc[m][nn] = __builtin_amdgcn_mfma_f32_16x16x32_bf16(av[m], bv[nn], acc[m][nn], 0, 0, 0);
        __syncthreads();
    }

    // epilogue: bare exp2; mask only in the last panel
    int i0w = i0 + wrow * 64;
    int j0w = j0 + wcol * 64;
    bool diag = (bj == bi);
    if (bj == T - 1) {
#pragma unroll
        for (int m = 0; m < 4; ++m)
#pragma unroll
            for (int nn = 0; nn < 4; ++nn) {
                int gj = j0w + nn * 16 + l15;
                bool jok = gj < n;
#pragma unroll
                for (int r = 0; r < 4; ++r) {
                    int gi = i0w + m * 16 + lg * 4 + r;
                    acc[m][nn][r] = (jok && gi < n) ? __builtin_exp2f(acc[m][nn][r]) : 0.f;
                }
            }
    } else {
#pragma unroll
        for (int m = 0; m < 4; ++m)
#pragma unroll
            for (int nn = 0; nn < 4; ++nn)
#pragma unroll
                for (int r = 0; r < 4; ++r)
                    acc[m][nn][r] = __builtin_exp2f(acc[m][nn][r]);
    }
    float* rowslot = P2d + (size_t)(2 * bj + wcol) * Npad;
#pragma unroll
    for (int m = 0; m < 4; ++m) {
#pragma unroll
        for (int r = 0; r < 4; ++r) {
            float v = acc[m][0][r] + acc[m][1][r] + acc[m][2][r] + acc[m][3][r];
            v += __shfl_xor(v, 1, 64);
            v += __shfl_xor(v, 2, 64);
            v += __shfl_xor(v, 4, 64);
            v += __shfl_xor(v, 8, 64);
            if (l15 == 0) {
                int gi = i0w + m * 16 + lg * 4 + r;
                if (gi < n) rowslot[gi] = v;
            }
        }
    }
    if (!diag) {
        float* colslot = P2d + (size_t)(2 * bi + wrow) * Npad;
#pragma unroll
        for (int nn = 0; nn < 4; ++nn) {
            float v = 0.f;
#pragma unroll
            for (int m = 0; m < 4; ++m)
#pragma unroll
                for (int r = 0; r < 4; ++r) v += acc[m][nn][r];
            v += __shfl_xor(v, 16, 64);
            v += __shfl_xor(v, 32, 64);
            if (lg == 0) {
                int gj = j0w + nn * 16 + l15;
                if (gj < n) colslot[gj] = v;
            }
        }
    }
}

// ---------------------------------------------------------------------------
// Fold: all 2T slots are written for every node -> plain sum, no memset.
// ---------------------------------------------------------------------------
__global__ void fold_kernel(const float* __restrict__ P2d, float* __restrict__ R,
                            int n, int slots, int Npad) {
    int i = blockIdx.x * 256 + threadIdx.x;
    if (i >= n) return;
    const float* p = P2d + i;
    float s0 = 0.f, s1 = 0.f, s2 = 0.f, s3 = 0.f;
    int sl = 0;
    for (; sl + 4 <= slots; sl += 4) {
        s0 += p[(size_t)(sl + 0) * Npad];
        s1 += p[(size_t)(sl + 1) * Npad];
        s2 += p[(size_t)(sl + 2) * Npad];
        s3 += p[(size_t)(sl + 3) * Npad];
    }
    for (; sl < slots; ++sl) s0 += p[(size_t)sl * Npad];
    R[i] = (s0 + s1) + (s2 + s3);
}

__global__ void loss_kernel(const float* __restrict__ R, const float* __restrict__ dvec,
                            float* __restrict__ out_loss, int n) {
    __shared__ float s[1024];
    int t = threadIdx.x;
    float sum = 0.f;
    for (int i = t; i < n; i += 1024) {
        float d   = dvec[i];
        float off = R[i] - d;
        sum += -logf(d / (off + off));
    }
    s[t] = sum;
    __syncthreads();
    for (int o = 512; o > 0; o >>= 1) {
        if (t < o) s[t] += s[t + o];
        __syncthreads();
    }
    if (t == 0) *out_loss = s[0] / n;
}

// ---------------------------------------------------------------------------
extern "C" void kernel_launch(void* const* d_in, const int* in_sizes, int n_in,
                              void* d_out, int out_size, void* d_ws, size_t ws_size,
                              hipStream_t stream) {
    const float* x   = (const float*)d_in[0];
    const int*   src = (const int*)d_in[1];
    const int*   dst = (const int*)d_in[2];
    const float* W0  = (const float*)d_in[3];
    const float* a0s = (const float*)d_in[4];
    const float* a0d = (const float*)d_in[5];
    const float* W1  = (const float*)d_in[6];
    const float* a1s = (const float*)d_in[7];
    const float* a1d = (const float*)d_in[8];
    const float* W2  = (const float*)d_in[9];
    const float* a2s = (const float*)d_in[10];
    const float* a2d = (const float*)d_in[11];
    const float* Wout= (const float*)d_in[12];
    const float* aos = (const float*)d_in[13];
    const float* aod = (const float*)d_in[14];

    int N = in_sizes[0] / NN_F_IN;
    int E = in_sizes[1];
    int Npad = ((N + 127) / 128) * 128;
    int T = Npad / 128;
    int nwg = T * (T + 1) / 2;
    float* out = (float*)d_out;

    char*  ws  = (char*)d_ws;
    size_t off = 0;
    auto alloc = [&](size_t bytes) -> void* {
        void* p = ws + off;
        off += bytes;
        off = (off + 255) & ~(size_t)255;
        return p;
    };
    size_t hbBytes = (size_t)N * 320 * 2;
    size_t znBytes = (size_t)Npad * NN_HID * 2;
    unsigned short* Hb = (unsigned short*)alloc(hbBytes > znBytes ? hbBytes : znBytes);
    short* znb = (short*)Hb;  // alias: znb live only between rownorm and gram
    unsigned short* Bl = (unsigned short*)alloc((size_t)N * NN_HID * 2);
    unsigned short* Bc = (unsigned short*)alloc((size_t)N * NN_HID * 2);
    size_t xbBytes = (size_t)N * NN_F_IN * 2;
    size_t p2Bytes = (size_t)2 * T * Npad * 4;
    void* XbP2d = alloc(xbBytes > p2Bytes ? xbBytes : p2Bytes);
    unsigned short* Xb  = (unsigned short*)XbP2d;  // live: prep..fc L0
    float*          P2d = (float*)XbP2d;           // live: gram..fold
    unsigned short* Wt0 = (unsigned short*)alloc((size_t)256 * 512 * 2);
    unsigned short* Wt1 = (unsigned short*)alloc((size_t)256 * 256 * 2);
    unsigned short* Wt2 = (unsigned short*)alloc((size_t)256 * 256 * 2);
    unsigned short* Wto = (unsigned short*)alloc((size_t)384 * 256 * 2);
    float* es     = (float*)alloc((size_t)N * NN_HEADS * 4);
    float* ed     = (float*)alloc((size_t)N * NN_HEADS * 4);
    float* wC     = (float*)alloc((size_t)E * NN_HEADS * 4);
    float* zinvA  = (float*)alloc((size_t)N * NN_HEADS * 4);
    float* Rrow   = (float*)alloc((size_t)N * 4);
    float* dvec   = (float*)alloc((size_t)N * 4);
    int*   counts = (int*)alloc((size_t)N * 4);
    int*   rs     = (int*)alloc((size_t)(N + 1) * 4);
    int*   cursor = (int*)alloc((size_t)N * 4);
    int*   csr    = (int*)alloc((size_t)E * 4);

    // ---- CSR build
    hipMemsetAsync(counts, 0, (size_t)N * 4, stream);
    count_kernel<<<(E + 255) / 256, 256, 0, stream>>>(dst, counts, E);
    scan_kernel<<<1, 1024, 0, stream>>>(counts, rs, cursor, N);
    scatter_kernel<<<(E + 255) / 256, 256, 0, stream>>>(src, dst, cursor, csr, E);

    // ---- fused prep (X + 4 W casts)
    int n4X = N * NN_F_IN / 4;
    int prepTotal = n4X + 256 * 512 + 256 * 256 + 256 * 256 + 384 * 256;
    prep_kernel<<<(prepTotal + 255) / 256, 256, 0, stream>>>(
        x, W0, W1, W2, Wout, Xb, Wt0, Wt1, Wt2, Wto, n4X);

    int atGrid = (N * NN_HEADS + 255) / 256;
    int ghGrid = (N + 3) / 4;
    int mT64 = (N + 63) / 64;

    // ---- layer 0: Xb -> Hb -> Bl
    fc_mfma<<<dim3(4, mT64), 256, 0, stream>>>(Xb, Wt0, Hb, N, 512, 256, 256);
    attn_kernel<<<atGrid, 256, 0, stream>>>(Hb, a0s, a0d, es, ed, N, NN_FH);
    gather_hidden<<<ghGrid, 256, 0, stream>>>(Hb, es, ed, csr, rs, nullptr, Bl, N, -1.f);

    // ---- layer 1: Bl -> Hb -> Bc (beta = 0.5/3)
    fc_mfma<<<dim3(4, mT64), 256, 0, stream>>>(Bl, Wt1, Hb, N, 256, 256, 256);
    attn_kernel<<<atGrid, 256, 0, stream>>>(Hb, a1s, a1d, es, ed, N, NN_FH);
    gather_hidden<<<ghGrid, 256, 0, stream>>>(Hb, es, ed, csr, rs, Bl, Bc, N, LAMDA_F / 3.f);

    // ---- layer 2: Bc -> Hb -> Bl (beta = 0.5/4)
    fc_mfma<<<dim3(4, mT64), 256, 0, stream>>>(Bc, Wt2, Hb, N, 256, 256, 256);
    attn_kernel<<<atGrid, 256, 0, stream>>>(Hb, a2s, a2d, es, ed, N, NN_FH);
    gather_hidden<<<ghGrid, 256, 0, stream>>>(Hb, es, ed, csr, rs, Bc, Bl, N, LAMDA_F / 4.f);

    // ---- bind_loss(Bl): znb (aliases Hb, pad rows zeroed in rownorm)
    rownorm_kernel<<<Npad, 256, 0, stream>>>(Bl, znb, dvec, N);
    gram_mfma<<<nwg, 256, 0, stream>>>(znb, P2d, N, T, nwg, Npad);
    fold_kernel<<<(N + 255) / 256, 256, 0, stream>>>(P2d, Rrow, N, 2 * T, Npad);
    loss_kernel<<<1, 1024, 0, stream>>>(Rrow, dvec, out + (size_t)N * NN_NCLASS, N);

    // ---- output layer: Bl -> Hb(320) -> d_out
    fc_mfma<<<dim3(5, mT64), 256, 0, stream>>>(Bl, Wto, Hb, N, 256, 320, 320);
    attn_kernel<<<atGrid, 256, 0, stream>>>(Hb, aos, aod, es, ed, N, NN_NCLASS);
    edge_wz<<<ghGrid, 256, 0, stream>>>(es, ed, csr, rs, wC, zinvA, N);
    gather_final<<<N, NN_HEADS * NN_NCLASS, 0, stream>>>(Hb, wC, zinvA, csr, rs, out, N);
}

// Round 13
// 366.891 us; speedup vs baseline: 1.1411x; 1.0488x over previous
//
#include <hip/hip_runtime.h>
#include <hip/hip_bf16.h>
#include <math.h>

#define NN_F_IN   512
#define NN_HID    256
#define NN_HEADS  8
#define NN_FH     32
#define NN_NCLASS 40
#define TAU_F     0.5f
#define LAMDA_F   0.5f
// sqrt(2 * log2(e)) : makes gram epilogue a bare exp2
#define ZN_SCALE  1.6986436f

typedef __attribute__((ext_vector_type(8))) short bf16x8;
typedef __attribute__((ext_vector_type(4))) float f32x4;

typedef __attribute__((address_space(1))) unsigned int gu32_t;
typedef __attribute__((address_space(3))) unsigned int lu32_t;

static __device__ __forceinline__ float lrelu02(float x) { return x >= 0.f ? x : 0.2f * x; }
static __device__ __forceinline__ float elu1(float x)    { return x > 0.f ? x : expm1f(x); }
static __device__ __forceinline__ float b2f(unsigned short u) {
    unsigned int x = ((unsigned int)u) << 16;
    return __uint_as_float(x);
}
static __device__ __forceinline__ unsigned short f2b(float f) {
    __hip_bfloat16 hb = __float2bfloat16(f);
    return *reinterpret_cast<unsigned short*>(&hb);
}

// ---------------------------------------------------------------------------
// Fused prep: X cast (float4-wide) + 4 transposed W casts, one launch.
// ---------------------------------------------------------------------------
__global__ void prep_kernel(const float* __restrict__ x,
                            const float* __restrict__ W0, const float* __restrict__ W1,
                            const float* __restrict__ W2, const float* __restrict__ Wo,
                            unsigned short* __restrict__ Xb,
                            unsigned short* __restrict__ Wt0, unsigned short* __restrict__ Wt1,
                            unsigned short* __restrict__ Wt2, unsigned short* __restrict__ Wto,
                            int n4X) {
    int i = blockIdx.x * 256 + threadIdx.x;
    if (i < n4X) {
        float4 v = *(const float4*)(x + (size_t)i * 4);
        ushort4 o;
        o.x = f2b(v.x); o.y = f2b(v.y); o.z = f2b(v.z); o.w = f2b(v.w);
        *(ushort4*)(Xb + (size_t)i * 4) = o;
        return;
    }
    i -= n4X;
    if (i < 256 * 512) {            // Wt0: Np=256, K=512, Nc=256
        int np = i >> 9, k = i & 511;
        Wt0[i] = f2b(W0[(size_t)k * 256 + np]);
        return;
    }
    i -= 256 * 512;
    if (i < 256 * 256) {            // Wt1
        int np = i >> 8, k = i & 255;
        Wt1[i] = f2b(W1[(size_t)k * 256 + np]);
        return;
    }
    i -= 256 * 256;
    if (i < 256 * 256) {            // Wt2
        int np = i >> 8, k = i & 255;
        Wt2[i] = f2b(W2[(size_t)k * 256 + np]);
        return;
    }
    i -= 256 * 256;
    if (i < 384 * 256) {            // Wto: Np=384, K=256, Nc=320
        int np = i >> 8, k = i & 255;
        Wto[i] = f2b(np < 320 ? Wo[(size_t)k * 320 + np] : 0.f);
    }
}

// ---------------------------------------------------------------------------
// MFMA GEMM + FUSED attention dots (hidden layers, ncols=256, FH=32).
// Block = 4 waves 2x2 -> 64x64 tile; each 32-col half = exactly one head:
// hh = blockIdx.x*2 + wcol. es/ed computed from fp32 acc via 16-lane reduce.
// ---------------------------------------------------------------------------
__global__ __launch_bounds__(256) void fc_attn_mfma(
    const unsigned short* __restrict__ A, const unsigned short* __restrict__ B,
    unsigned short* __restrict__ H, const float* __restrict__ As_,
    const float* __restrict__ Ad_, float* __restrict__ es, float* __restrict__ ed,
    int M, int K) {
    const int ldH = 256;
    int t = threadIdx.x, lane = t & 63, wid = t >> 6;
    int wrow = wid >> 1, wcol = wid & 1;
    int l15 = lane & 15, lg = lane >> 4;
    int mbase = blockIdx.y * 64 + wrow * 32;
    int nbase = blockIdx.x * 64 + wcol * 32;

    const unsigned short* Ap[2];
    const unsigned short* Bp[2];
#pragma unroll
    for (int m = 0; m < 2; ++m) {
        int rr = mbase + m * 16 + l15;
        if (rr > M - 1) rr = M - 1;
        Ap[m] = A + (size_t)rr * K + lg * 8;
        Bp[m] = B + (size_t)(nbase + m * 16 + l15) * K + lg * 8;
    }
    f32x4 acc[2][2];
#pragma unroll
    for (int m = 0; m < 2; ++m)
#pragma unroll
        for (int nn = 0; nn < 2; ++nn)
#pragma unroll
            for (int r = 0; r < 4; ++r) acc[m][nn][r] = 0.f;

    bf16x8 aP[2], bP[2], aQ[2], bQ[2];
#pragma unroll
    for (int m = 0; m < 2; ++m) {
        aP[m] = *(const bf16x8*)(Ap[m]);
        bP[m] = *(const bf16x8*)(Bp[m]);
    }
    int nhalf = K >> 6;
    int kk = 32;
    for (int it = 0; it < nhalf; ++it) {
#pragma unroll
        for (int m = 0; m < 2; ++m) {
            aQ[m] = *(const bf16x8*)(Ap[m] + kk);
            bQ[m] = *(const bf16x8*)(Bp[m] + kk);
        }
#pragma unroll
        for (int m = 0; m < 2; ++m)
#pragma unroll
            for (int nn = 0; nn < 2; ++nn)
                acc[m][nn] = __builtin_amdgcn_mfma_f32_16x16x32_bf16(aP[m], bP[nn], acc[m][nn], 0, 0, 0);
        if (it + 1 < nhalf) {
#pragma unroll
            for (int m = 0; m < 2; ++m) {
                aP[m] = *(const bf16x8*)(Ap[m] + kk + 32);
                bP[m] = *(const bf16x8*)(Bp[m] + kk + 32);
            }
        }
#pragma unroll
        for (int m = 0; m < 2; ++m)
#pragma unroll
            for (int nn = 0; nn < 2; ++nn)
                acc[m][nn] = __builtin_amdgcn_mfma_f32_16x16x32_bf16(aQ[m], bQ[nn], acc[m][nn], 0, 0, 0);
        kk += 64;
    }
    // H store
#pragma unroll
    for (int m = 0; m < 2; ++m) {
#pragma unroll
        for (int nn = 0; nn < 2; ++nn) {
            int col = nbase + nn * 16 + l15;
#pragma unroll
            for (int r = 0; r < 4; ++r) {
                int row = mbase + m * 16 + lg * 4 + r;
                if (row < M) H[(size_t)row * ldH + col] = f2b(acc[m][nn][r]);
            }
        }
    }
    // fused attn dots: head hh covers this wave's 32 cols
    int hh = blockIdx.x * 2 + wcol;
    float a0 = As_[hh * 32 + l15], a1 = As_[hh * 32 + 16 + l15];
    float d0 = Ad_[hh * 32 + l15], d1 = Ad_[hh * 32 + 16 + l15];
#pragma unroll
    for (int m = 0; m < 2; ++m) {
#pragma unroll
        for (int r = 0; r < 4; ++r) {
            float ps = acc[m][0][r] * a0 + acc[m][1][r] * a1;
            float pd = acc[m][0][r] * d0 + acc[m][1][r] * d1;
            ps += __shfl_xor(ps, 1, 64); pd += __shfl_xor(pd, 1, 64);
            ps += __shfl_xor(ps, 2, 64); pd += __shfl_xor(pd, 2, 64);
            ps += __shfl_xor(ps, 4, 64); pd += __shfl_xor(pd, 4, 64);
            ps += __shfl_xor(ps, 8, 64); pd += __shfl_xor(pd, 8, 64);
            if (l15 == 0) {
                int row = mbase + m * 16 + lg * 4 + r;
                if (row < M) {
                    es[row * NN_HEADS + hh] = ps;
                    ed[row * NN_HEADS + hh] = pd;
                }
            }
        }
    }
}

// ---------------------------------------------------------------------------
// Plain MFMA GEMM (final layer, ncols=320)
// ---------------------------------------------------------------------------
__global__ __launch_bounds__(256) void fc_mfma(const unsigned short* __restrict__ A,
                                               const unsigned short* __restrict__ B,
                                               unsigned short* __restrict__ H,
                                               int M, int K, int ncols, int ldH) {
    int t = threadIdx.x, lane = t & 63, wid = t >> 6;
    int wrow = wid >> 1, wcol = wid & 1;
    int l15 = lane & 15, lg = lane >> 4;
    int mbase = blockIdx.y * 64 + wrow * 32;
    int nbase = blockIdx.x * 64 + wcol * 32;

    const unsigned short* Ap[2];
    const unsigned short* Bp[2];
#pragma unroll
    for (int m = 0; m < 2; ++m) {
        int rr = mbase + m * 16 + l15;
        if (rr > M - 1) rr = M - 1;
        Ap[m] = A + (size_t)rr * K + lg * 8;
        Bp[m] = B + (size_t)(nbase + m * 16 + l15) * K + lg * 8;
    }
    f32x4 acc[2][2];
#pragma unroll
    for (int m = 0; m < 2; ++m)
#pragma unroll
        for (int nn = 0; nn < 2; ++nn)
#pragma unroll
            for (int r = 0; r < 4; ++r) acc[m][nn][r] = 0.f;

    bf16x8 aP[2], bP[2], aQ[2], bQ[2];
#pragma unroll
    for (int m = 0; m < 2; ++m) {
        aP[m] = *(const bf16x8*)(Ap[m]);
        bP[m] = *(const bf16x8*)(Bp[m]);
    }
    int nhalf = K >> 6;
    int kk = 32;
    for (int it = 0; it < nhalf; ++it) {
#pragma unroll
        for (int m = 0; m < 2; ++m) {
            aQ[m] = *(const bf16x8*)(Ap[m] + kk);
            bQ[m] = *(const bf16x8*)(Bp[m] + kk);
        }
#pragma unroll
        for (int m = 0; m < 2; ++m)
#pragma unroll
            for (int nn = 0; nn < 2; ++nn)
                acc[m][nn] = __builtin_amdgcn_mfma_f32_16x16x32_bf16(aP[m], bP[nn], acc[m][nn], 0, 0, 0);
        if (it + 1 < nhalf) {
#pragma unroll
            for (int m = 0; m < 2; ++m) {
                aP[m] = *(const bf16x8*)(Ap[m] + kk + 32);
                bP[m] = *(const bf16x8*)(Bp[m] + kk + 32);
            }
        }
#pragma unroll
        for (int m = 0; m < 2; ++m)
#pragma unroll
            for (int nn = 0; nn < 2; ++nn)
                acc[m][nn] = __builtin_amdgcn_mfma_f32_16x16x32_bf16(aQ[m], bQ[nn], acc[m][nn], 0, 0, 0);
        kk += 64;
    }
#pragma unroll
    for (int m = 0; m < 2; ++m) {
#pragma unroll
        for (int nn = 0; nn < 2; ++nn) {
            int col = nbase + nn * 16 + l15;
            if (col >= ncols) continue;
#pragma unroll
            for (int r = 0; r < 4; ++r) {
                int row = mbase + m * 16 + lg * 4 + r;
                if (row < M) H[(size_t)row * ldH + col] = f2b(acc[m][nn][r]);
            }
        }
    }
}

// ---------------------------------------------------------------------------
// es/ed dot products (final layer, df=NCLASS=40 — heads not 64-col aligned)
// ---------------------------------------------------------------------------
__global__ void attn_kernel(const unsigned short* __restrict__ Hm, const float* __restrict__ As,
                            const float* __restrict__ Ad, float* __restrict__ es,
                            float* __restrict__ ed, int n, int df) {
    int idx = blockIdx.x * blockDim.x + threadIdx.x;
    if (idx >= n * NN_HEADS) return;
    int nn = idx / NN_HEADS, hh = idx - nn * NN_HEADS;
    const unsigned short* hp = Hm + (size_t)nn * NN_HEADS * df + hh * df;
    const float* ap = As + hh * df;
    const float* bp = Ad + hh * df;
    float s1 = 0.f, s2 = 0.f;
    for (int d = 0; d < df; d += 4) {
        ushort4 hv = *(const ushort4*)(hp + d);
        float4 av = *(const float4*)(ap + d);
        float4 bv = *(const float4*)(bp + d);
        float h0 = b2f(hv.x), h1 = b2f(hv.y), h2 = b2f(hv.z), h3 = b2f(hv.w);
        s1 += h0 * av.x + h1 * av.y + h2 * av.z + h3 * av.w;
        s2 += h0 * bv.x + h1 * bv.y + h2 * bv.z + h3 * bv.w;
    }
    es[idx] = s1;
    ed[idx] = s2;
}

// ---------------------------------------------------------------------------
// Edge weights (FINAL LAYER ONLY — 40x redundancy there justifies the pass).
// ---------------------------------------------------------------------------
__global__ __launch_bounds__(256) void edge_wz(
    const float* __restrict__ es, const float* __restrict__ ed,
    const int* __restrict__ csr_src, const int* __restrict__ row_start,
    float* __restrict__ wC, float* __restrict__ zinv, int n) {
    int lane = threadIdx.x & 63;
    int nn   = blockIdx.x * 4 + (threadIdx.x >> 6);
    if (nn >= n) return;
    int s0 = row_start[nn], s1 = row_start[nn + 1];
    int h    = lane & 7;
    int slot = lane >> 3;
    float edh = ed[nn * NN_HEADS + h];
    float z = 0.f;
    for (int e = s0 + slot; e < s1; e += 8) {
        int sv = csr_src[e];
        float w = __expf(lrelu02(es[sv * NN_HEADS + h] + edh));
        wC[(size_t)e * NN_HEADS + h] = w;
        z += w;
    }
    z += __shfl_xor(z, 8, 64);
    z += __shfl_xor(z, 16, 64);
    z += __shfl_xor(z, 32, 64);
    if (slot == 0) zinv[nn * NN_HEADS + h] = 1.f / z;
}

// ---------------------------------------------------------------------------
// CSR build
// ---------------------------------------------------------------------------
__global__ void count_kernel(const int* __restrict__ dst, int* __restrict__ counts, int E) {
    int e = blockIdx.x * blockDim.x + threadIdx.x;
    if (e < E) atomicAdd(&counts[dst[e]], 1);
}

__global__ void scan_kernel(const int* __restrict__ counts, int* __restrict__ row_start,
                            int* __restrict__ cursor, int n) {
    __shared__ int s[1024];
    int t  = threadIdx.x;
    int ch = (n + 1023) / 1024;
    int lo = t * ch;
    int sum = 0;
    for (int j = 0; j < ch; ++j) {
        int i = lo + j;
        if (i < n) sum += counts[i];
    }
    s[t] = sum;
    __syncthreads();
    for (int off = 1; off < 1024; off <<= 1) {
        int v = 0;
        if (t >= off) v = s[t - off];
        __syncthreads();
        s[t] += v;
        __syncthreads();
    }
    int run = (t == 0) ? 0 : s[t - 1];
    for (int j = 0; j < ch; ++j) {
        int i = lo + j;
        if (i < n) {
            row_start[i] = run;
            cursor[i] = run;
            run += counts[i];
        }
    }
    if (t == 1023) row_start[n] = s[1023];
}

__global__ void scatter_kernel(const int* __restrict__ src, const int* __restrict__ dst,
                               int* __restrict__ cursor, int* __restrict__ csr_src, int E) {
    int e = blockIdx.x * blockDim.x + threadIdx.x;
    if (e < E) {
        int d   = dst[e];
        int pos = atomicAdd(&cursor[d], 1);
        csr_src[pos] = src[e];
    }
}

// ---------------------------------------------------------------------------
// Hidden-layer gather, FUSED edge weights; optional FUSED rownorm (layer 2):
// the wave holds the full 256-value output row -> 64-lane sq-sum reduce,
// write scaled-bf16 zn + analytic diagonal inline.
// ---------------------------------------------------------------------------
__global__ __launch_bounds__(256) void gather_hidden(
    const unsigned short* __restrict__ Hm, const float* __restrict__ es,
    const float* __restrict__ ed, const int* __restrict__ csr_src,
    const int* __restrict__ row_start, const unsigned short* __restrict__ last,
    unsigned short* __restrict__ out, int n, float beta,
    unsigned short* __restrict__ znb, float* __restrict__ dvec) {
    int lane = threadIdx.x & 63;
    int nn   = blockIdx.x * 4 + (threadIdx.x >> 6);
    if (nn >= n) return;
    int s0 = row_start[nn], s1 = row_start[nn + 1];
    int h2 = lane >> 3;
    float edh = ed[nn * NN_HEADS + h2];

    float zacc = 0.f;
    float a0 = 0.f, a1 = 0.f, a2 = 0.f, a3 = 0.f;
    int fullEnd = s0 + ((s1 - s0) & ~7);
    int e = s0;
    for (; e < fullEnd; e += 8) {
        int idx[8];
        float q[8];
#pragma unroll
        for (int j = 0; j < 8; ++j) idx[j] = csr_src[e + j];
#pragma unroll
        for (int j = 0; j < 8; ++j) q[j] = es[idx[j] * NN_HEADS + h2];
        ushort4 r[8];
#pragma unroll
        for (int j = 0; j < 8; ++j) r[j] = *(const ushort4*)&Hm[(size_t)idx[j] * NN_HID + lane * 4];
#pragma unroll
        for (int j = 0; j < 8; ++j) {
            float w = __expf(lrelu02(q[j] + edh));
            zacc += w;
            a0 += w * b2f(r[j].x); a1 += w * b2f(r[j].y);
            a2 += w * b2f(r[j].z); a3 += w * b2f(r[j].w);
        }
    }
    if (e < s1) {
        int c = s1 - e;
        int idx[8];
        float q[8];
#pragma unroll
        for (int j = 0; j < 8; ++j) idx[j] = csr_src[(j < c) ? e + j : e];
#pragma unroll
        for (int j = 0; j < 8; ++j) q[j] = es[idx[j] * NN_HEADS + h2];
        ushort4 r[8];
#pragma unroll
        for (int j = 0; j < 8; ++j) r[j] = *(const ushort4*)&Hm[(size_t)idx[j] * NN_HID + lane * 4];
#pragma unroll
        for (int j = 0; j < 8; ++j) {
            if (j < c) {
                float w = __expf(lrelu02(q[j] + edh));
                zacc += w;
                a0 += w * b2f(r[j].x); a1 += w * b2f(r[j].y);
                a2 += w * b2f(r[j].z); a3 += w * b2f(r[j].w);
            }
        }
    }
    float zi = 1.f / zacc;
    float v0 = elu1(a0 * zi), v1 = elu1(a1 * zi), v2 = elu1(a2 * zi), v3 = elu1(a3 * zi);
    if (beta >= 0.f) {
        ushort4 lv = *(const ushort4*)&last[(size_t)nn * NN_HID + lane * 4];
        v0 = beta * b2f(lv.x) + (1.f - beta) * v0;
        v1 = beta * b2f(lv.y) + (1.f - beta) * v1;
        v2 = beta * b2f(lv.z) + (1.f - beta) * v2;
        v3 = beta * b2f(lv.w) + (1.f - beta) * v3;
    }
    ushort4 o;
    o.x = f2b(v0); o.y = f2b(v1); o.z = f2b(v2); o.w = f2b(v3);
    *(ushort4*)&out[(size_t)nn * NN_HID + lane * 4] = o;

    if (znb) {
        float ss = v0 * v0 + v1 * v1 + v2 * v2 + v3 * v3;
        ss += __shfl_xor(ss, 1, 64);
        ss += __shfl_xor(ss, 2, 64);
        ss += __shfl_xor(ss, 4, 64);
        ss += __shfl_xor(ss, 8, 64);
        ss += __shfl_xor(ss, 16, 64);
        ss += __shfl_xor(ss, 32, 64);
        float m = fmaxf(sqrtf(ss), 1e-12f);
        float sc = ZN_SCALE / m;
        ushort4 zo;
        zo.x = f2b(v0 * sc); zo.y = f2b(v1 * sc);
        zo.z = f2b(v2 * sc); zo.w = f2b(v3 * sc);
        *(ushort4*)&znb[(size_t)nn * NN_HID + lane * 4] = zo;
        if (lane == 0) dvec[nn] = __expf((ss / (m * m)) * (1.f / TAU_F));
    }
}

// ---------------------------------------------------------------------------
// Final layer gather: weighted sum + head-mean + log_softmax -> d_out
// ---------------------------------------------------------------------------
__global__ void gather_final(const unsigned short* __restrict__ Hm, const float* __restrict__ wC,
                             const float* __restrict__ zinv, const int* __restrict__ csr_src,
                             const int* __restrict__ row_start, float* __restrict__ dout, int n) {
    int nn = blockIdx.x;
    __shared__ float accs[NN_HEADS * NN_NCLASS];
    int t = threadIdx.x;  // 0..319
    int s0 = row_start[nn], s1 = row_start[nn + 1];
    int hh = t / NN_NCLASS;
    float acc = 0.f;
    const int LD = NN_HEADS * NN_NCLASS;
    int fullEnd = s0 + ((s1 - s0) & ~7);
    int e = s0;
    for (; e < fullEnd; e += 8) {
        int idx[8];
        float wv[8];
#pragma unroll
        for (int j = 0; j < 8; ++j) {
            idx[j] = csr_src[e + j];
            wv[j]  = wC[(size_t)(e + j) * NN_HEADS + hh];
        }
        float v[8];
#pragma unroll
        for (int j = 0; j < 8; ++j) v[j] = b2f(Hm[(size_t)idx[j] * LD + t]);
#pragma unroll
        for (int j = 0; j < 8; ++j) acc += wv[j] * v[j];
    }
    if (e < s1) {
        int c = s1 - e;
        int idx[8];
        float wv[8];
#pragma unroll
        for (int j = 0; j < 8; ++j) {
            int p = (j < c) ? e + j : e;
            idx[j] = csr_src[p];
            wv[j]  = wC[(size_t)p * NN_HEADS + hh];
        }
        float v[8];
#pragma unroll
        for (int j = 0; j < 8; ++j) v[j] = b2f(Hm[(size_t)idx[j] * LD + t]);
#pragma unroll
        for (int j = 0; j < 8; ++j) {
            if (j < c) acc += wv[j] * v[j];
        }
    }
    accs[t] = acc * zinv[nn * NN_HEADS + hh];
    __syncthreads();
    if (t < 64) {
        float v = -INFINITY;
        if (t < NN_NCLASS) {
            float sacc = 0.f;
#pragma unroll
            for (int h2 = 0; h2 < NN_HEADS; ++h2) sacc += accs[h2 * NN_NCLASS + t];
            v = sacc * (1.f / NN_HEADS);
        }
        float mx = v;
#pragma unroll
        for (int o = 1; o < 64; o <<= 1) mx = fmaxf(mx, __shfl_xor(mx, o, 64));
        float ex = (t < NN_NCLASS) ? expf(v - mx) : 0.f;
        float se = ex;
#pragma unroll
        for (int o = 1; o < 64; o <<= 1) se += __shfl_xor(se, o, 64);
        if (t < NN_NCLASS) dout[(size_t)nn * NN_NCLASS + t] = (v - mx) - logf(se);
    }
}

// ---------------------------------------------------------------------------
// Symmetric gram rowsums — 2-PHASE DOUBLE-BUFFERED m97 structure:
// 4 waves, 128x128 tile, BK=32, 8 K-steps; LDS 2 buffers x 16KB staged via
// global_load_lds width=16. STAGE(next buf) issued BEFORE compute(cur) so
// loads get a compute-phase head start (guide T3 minimum 2-phase recipe).
// Bank swizzle (slot = kc ^ ((row>>1)&3)) on source AND read (rule #21).
// Epilogue: bare exp2 (zn pre-scaled), last-panel-only masking, R10 slots:
//   row-partials -> slot 2*bj+wcol ; col-partials -> slot 2*bi+wrow.
// ---------------------------------------------------------------------------
__global__ __launch_bounds__(256) void gram_mfma(const short* __restrict__ znb,
                                                 float* __restrict__ P2d, int n,
                                                 int T, int nwg, int Npad) {
    __shared__ short As[2][128 * 32];
    __shared__ short Bs[2][128 * 32];

    int b = blockIdx.x;
    int q = nwg >> 3, r8 = nwg & 7, xc = b & 7, oo = b >> 3;
    int sid = (xc < r8 ? xc * (q + 1) : r8 * (q + 1) + (xc - r8) * q) + oo;
    int bi = 0, rem = sid;
    while (rem >= T - bi) { rem -= T - bi; ++bi; }
    int bj = bi + rem;
    int i0 = bi * 128, j0 = bj * 128;

    int t    = threadIdx.x;
    int lane = t & 63;
    int wid  = t >> 6;
    int wrow = wid >> 1, wcol = wid & 1;
    int l15  = lane & 15, lg = lane >> 4;

    // staging: wave covers chunks 2*wid, 2*wid+1; chunk = 16 rows x 32 k.
    int srow0 = 16 * (2 * wid + 0) + (lane >> 2);
    int srow1 = 16 * (2 * wid + 1) + (lane >> 2);
    int kc    = lane & 3;
    int kc0   = kc ^ ((srow0 >> 1) & 3);
    int kc1   = kc ^ ((srow1 >> 1) & 3);
    const short* gA0 = znb + (size_t)(i0 + srow0) * NN_HID + kc0 * 8;
    const short* gA1 = znb + (size_t)(i0 + srow1) * NN_HID + kc1 * 8;
    const short* gB0 = znb + (size_t)(j0 + srow0) * NN_HID + kc0 * 8;
    const short* gB1 = znb + (size_t)(j0 + srow1) * NN_HID + kc1 * 8;
    int ldst0 = (2 * wid + 0) * 512 + lane * 8;
    int ldst1 = (2 * wid + 1) * 512 + lane * 8;

    auto stage = [&](int buf, int s) {
        int ko = s * 32;
        __builtin_amdgcn_global_load_lds((gu32_t*)(gA0 + ko), (lu32_t*)(&As[buf][ldst0]), 16, 0, 0);
        __builtin_amdgcn_global_load_lds((gu32_t*)(gA1 + ko), (lu32_t*)(&As[buf][ldst1]), 16, 0, 0);
        __builtin_amdgcn_global_load_lds((gu32_t*)(gB0 + ko), (lu32_t*)(&Bs[buf][ldst0]), 16, 0, 0);
        __builtin_amdgcn_global_load_lds((gu32_t*)(gB1 + ko), (lu32_t*)(&Bs[buf][ldst1]), 16, 0, 0);
    };

    f32x4 acc[4][4];
#pragma unroll
    for (int m = 0; m < 4; ++m)
#pragma unroll
        for (int nn = 0; nn < 4; ++nn)
#pragma unroll
            for (int r = 0; r < 4; ++r) acc[m][nn][r] = 0.f;

    stage(0, 0);
    __syncthreads();
#pragma unroll
    for (int s = 0; s < 8; ++s) {
        int cur = s & 1;
        if (s < 7) stage(cur ^ 1, s + 1);   // issue next-step loads first
        bf16x8 av[4], bv[4];
#pragma unroll
        for (int m = 0; m < 4; ++m) {
            int Ra = wrow * 64 + m * 16 + l15;
            int ca = lg ^ ((Ra >> 1) & 3);
            av[m] = *(const bf16x8*)&As[cur][Ra * 32 + ca * 8];
        }
#pragma unroll
        for (int m = 0; m < 4; ++m) {
            int Rb = wcol * 64 + m * 16 + l15;
            int cb = lg ^ ((Rb >> 1) & 3);
            bv[m] = *(const bf16x8*)&Bs[cur][Rb * 32 + cb * 8];
        }
#pragma unroll
        for (int m = 0; m < 4; ++m)
#pragma unroll
            for (int nn = 0; nn < 4; ++nn)
                acc[m][nn] = __builtin_amdgcn_mfma_f32_16x16x32_bf16(av[m], bv[nn], acc[m][nn], 0, 0, 0);
        __syncthreads();   // drains next-step loads + protects cur buffer
    }

    // epilogue: bare exp2; mask only in the last panel
    int i0w = i0 + wrow * 64;
    int j0w = j0 + wcol * 64;
    bool diag = (bj == bi);
    if (bj == T - 1) {
#pragma unroll
        for (int m = 0; m < 4; ++m)
#pragma unroll
            for (int nn = 0; nn < 4; ++nn) {
                int gj = j0w + nn * 16 + l15;
                bool jok = gj < n;
#pragma unroll
                for (int r = 0; r < 4; ++r) {
                    int gi = i0w + m * 16 + lg * 4 + r;
                    acc[m][nn][r] = (jok && gi < n) ? __builtin_exp2f(acc[m][nn][r]) : 0.f;
                }
            }
    } else {
#pragma unroll
        for (int m = 0; m < 4; ++m)
#pragma unroll
            for (int nn = 0; nn < 4; ++nn)
#pragma unroll
                for (int r = 0; r < 4; ++r)
                    acc[m][nn][r] = __builtin_exp2f(acc[m][nn][r]);
    }
    float* rowslot = P2d + (size_t)(2 * bj + wcol) * Npad;
#pragma unroll
    for (int m = 0; m < 4; ++m) {
#pragma unroll
        for (int r = 0; r < 4; ++r) {
            float v = acc[m][0][r] + acc[m][1][r] + acc[m][2][r] + acc[m][3][r];
            v += __shfl_xor(v, 1, 64);
            v += __shfl_xor(v, 2, 64);
            v += __shfl_xor(v, 4, 64);
            v += __shfl_xor(v, 8, 64);
            if (l15 == 0) {
                int gi = i0w + m * 16 + lg * 4 + r;
                if (gi < n) rowslot[gi] = v;
            }
        }
    }
    if (!diag) {
        float* colslot = P2d + (size_t)(2 * bi + wrow) * Npad;
#pragma unroll
        for (int nn = 0; nn < 4; ++nn) {
            float v = 0.f;
#pragma unroll
            for (int m = 0; m < 4; ++m)
#pragma unroll
                for (int r = 0; r < 4; ++r) v += acc[m][nn][r];
            v += __shfl_xor(v, 16, 64);
            v += __shfl_xor(v, 32, 64);
            if (lg == 0) {
                int gj = j0w + nn * 16 + l15;
                if (gj < n) colslot[gj] = v;
            }
        }
    }
}

// ---------------------------------------------------------------------------
// Fold: all 2T slots written for every node -> plain sum, no memset.
// ---------------------------------------------------------------------------
__global__ void fold_kernel(const float* __restrict__ P2d, float* __restrict__ R,
                            int n, int slots, int Npad) {
    int i = blockIdx.x * 256 + threadIdx.x;
    if (i >= n) return;
    const float* p = P2d + i;
    float s0 = 0.f, s1 = 0.f, s2 = 0.f, s3 = 0.f;
    int sl = 0;
    for (; sl + 4 <= slots; sl += 4) {
        s0 += p[(size_t)(sl + 0) * Npad];
        s1 += p[(size_t)(sl + 1) * Npad];
        s2 += p[(size_t)(sl + 2) * Npad];
        s3 += p[(size_t)(sl + 3) * Npad];
    }
    for (; sl < slots; ++sl) s0 += p[(size_t)sl * Npad];
    R[i] = (s0 + s1) + (s2 + s3);
}

__global__ void loss_kernel(const float* __restrict__ R, const float* __restrict__ dvec,
                            float* __restrict__ out_loss, int n) {
    __shared__ float s[1024];
    int t = threadIdx.x;
    float sum = 0.f;
    for (int i = t; i < n; i += 1024) {
        float d   = dvec[i];
        float off = R[i] - d;
        sum += -logf(d / (off + off));
    }
    s[t] = sum;
    __syncthreads();
    for (int o = 512; o > 0; o >>= 1) {
        if (t < o) s[t] += s[t + o];
        __syncthreads();
    }
    if (t == 0) *out_loss = s[0] / n;
}

// ---------------------------------------------------------------------------
extern "C" void kernel_launch(void* const* d_in, const int* in_sizes, int n_in,
                              void* d_out, int out_size, void* d_ws, size_t ws_size,
                              hipStream_t stream) {
    const float* x   = (const float*)d_in[0];
    const int*   src = (const int*)d_in[1];
    const int*   dst = (const int*)d_in[2];
    const float* W0  = (const float*)d_in[3];
    const float* a0s = (const float*)d_in[4];
    const float* a0d = (const float*)d_in[5];
    const float* W1  = (const float*)d_in[6];
    const float* a1s = (const float*)d_in[7];
    const float* a1d = (const float*)d_in[8];
    const float* W2  = (const float*)d_in[9];
    const float* a2s = (const float*)d_in[10];
    const float* a2d = (const float*)d_in[11];
    const float* Wout= (const float*)d_in[12];
    const float* aos = (const float*)d_in[13];
    const float* aod = (const float*)d_in[14];

    int N = in_sizes[0] / NN_F_IN;
    int E = in_sizes[1];
    int Npad = ((N + 127) / 128) * 128;
    int T = Npad / 128;
    int nwg = T * (T + 1) / 2;
    float* out = (float*)d_out;

    char*  ws  = (char*)d_ws;
    size_t off = 0;
    auto alloc = [&](size_t bytes) -> void* {
        void* p = ws + off;
        off += bytes;
        off = (off + 255) & ~(size_t)255;
        return p;
    };
    unsigned short* Hb = (unsigned short*)alloc((size_t)N * 320 * 2);
    unsigned short* znb = (unsigned short*)alloc((size_t)Npad * NN_HID * 2);  // dedicated (fused write)
    unsigned short* Bl = (unsigned short*)alloc((size_t)N * NN_HID * 2);
    unsigned short* Bc = (unsigned short*)alloc((size_t)N * NN_HID * 2);
    size_t xbBytes = (size_t)N * NN_F_IN * 2;
    size_t p2Bytes = (size_t)2 * T * Npad * 4;
    void* XbP2d = alloc(xbBytes > p2Bytes ? xbBytes : p2Bytes);
    unsigned short* Xb  = (unsigned short*)XbP2d;  // live: prep..fc L0
    float*          P2d = (float*)XbP2d;           // live: gram..fold
    unsigned short* Wt0 = (unsigned short*)alloc((size_t)256 * 512 * 2);
    unsigned short* Wt1 = (unsigned short*)alloc((size_t)256 * 256 * 2);
    unsigned short* Wt2 = (unsigned short*)alloc((size_t)256 * 256 * 2);
    unsigned short* Wto = (unsigned short*)alloc((size_t)384 * 256 * 2);
    float* es     = (float*)alloc((size_t)N * NN_HEADS * 4);
    float* ed     = (float*)alloc((size_t)N * NN_HEADS * 4);
    float* wC     = (float*)alloc((size_t)E * NN_HEADS * 4);
    float* zinvA  = (float*)alloc((size_t)N * NN_HEADS * 4);
    float* Rrow   = (float*)alloc((size_t)N * 4);
    float* dvec   = (float*)alloc((size_t)N * 4);
    int*   counts = (int*)alloc((size_t)N * 4);
    int*   rs     = (int*)alloc((size_t)(N + 1) * 4);
    int*   cursor = (int*)alloc((size_t)N * 4);
    int*   csr    = (int*)alloc((size_t)E * 4);

    // ---- CSR build + znb pad-row zeroing (overlaps with graph front)
    hipMemsetAsync(counts, 0, (size_t)N * 4, stream);
    if (Npad > N)
        hipMemsetAsync(znb + (size_t)N * NN_HID, 0, (size_t)(Npad - N) * NN_HID * 2, stream);
    count_kernel<<<(E + 255) / 256, 256, 0, stream>>>(dst, counts, E);
    scan_kernel<<<1, 1024, 0, stream>>>(counts, rs, cursor, N);
    scatter_kernel<<<(E + 255) / 256, 256, 0, stream>>>(src, dst, cursor, csr, E);

    // ---- fused prep (X + 4 W casts)
    int n4X = N * NN_F_IN / 4;
    int prepTotal = n4X + 256 * 512 + 256 * 256 + 256 * 256 + 384 * 256;
    prep_kernel<<<(prepTotal + 255) / 256, 256, 0, stream>>>(
        x, W0, W1, W2, Wout, Xb, Wt0, Wt1, Wt2, Wto, n4X);

    int atGrid = (N * NN_HEADS + 255) / 256;
    int ghGrid = (N + 3) / 4;
    int mT64 = (N + 63) / 64;

    // ---- layer 0: Xb -> Hb (+es/ed fused) -> Bl
    fc_attn_mfma<<<dim3(4, mT64), 256, 0, stream>>>(Xb, Wt0, Hb, a0s, a0d, es, ed, N, 512);
    gather_hidden<<<ghGrid, 256, 0, stream>>>(Hb, es, ed, csr, rs, nullptr, Bl, N, -1.f,
                                              nullptr, nullptr);

    // ---- layer 1: Bl -> Hb (+es/ed) -> Bc (beta = 0.5/3)
    fc_attn_mfma<<<dim3(4, mT64), 256, 0, stream>>>(Bl, Wt1, Hb, a1s, a1d, es, ed, N, 256);
    gather_hidden<<<ghGrid, 256, 0, stream>>>(Hb, es, ed, csr, rs, Bl, Bc, N, LAMDA_F / 3.f,
                                              nullptr, nullptr);

    // ---- layer 2: Bc -> Hb (+es/ed) -> Bl (beta = 0.5/4) + FUSED rownorm
    fc_attn_mfma<<<dim3(4, mT64), 256, 0, stream>>>(Bc, Wt2, Hb, a2s, a2d, es, ed, N, 256);
    gather_hidden<<<ghGrid, 256, 0, stream>>>(Hb, es, ed, csr, rs, Bc, Bl, N, LAMDA_F / 4.f,
                                              znb, dvec);

    // ---- bind_loss: gram on znb, fold, loss
    gram_mfma<<<nwg, 256, 0, stream>>>((const short*)znb, P2d, N, T, nwg, Npad);
    fold_kernel<<<(N + 255) / 256, 256, 0, stream>>>(P2d, Rrow, N, 2 * T, Npad);
    loss_kernel<<<1, 1024, 0, stream>>>(Rrow, dvec, out + (size_t)N * NN_NCLASS, N);

    // ---- output layer: Bl -> Hb(320) -> d_out
    fc_mfma<<<dim3(5, mT64), 256, 0, stream>>>(Bl, Wto, Hb, N, 256, 320, 320);
    attn_kernel<<<atGrid, 256, 0, stream>>>(Hb, aos, aod, es, ed, N, NN_NCLASS);
    edge_wz<<<ghGrid, 256, 0, stream>>>(es, ed, csr, rs, wC, zinvA, N);
    gather_final<<<N, NN_HEADS * NN_NCLASS, 0, stream>>>(Hb, wC, zinvA, csr, rs, out, N);
}